// Round 6
// baseline (720.652 us; speedup 1.0000x reference)
//
#include <hip/hip_runtime.h>
#include <hip/hip_bf16.h>
#include <stdint.h>

#define SEQ 2048
#define DIMSZ 4096
#define QKVN 6144   // 4096 Q + 1024 K + 1024 V

typedef __attribute__((ext_vector_type(8))) __bf16 bf16x8;
typedef __attribute__((ext_vector_type(4))) float f32x4;

// async global->LDS, 16B per lane; dest = wave-uniform base + lane*16
static __device__ __forceinline__ void gld_lds16(const void* g, void* l) {
  __builtin_amdgcn_global_load_lds(
      (__attribute__((address_space(1))) void*)(g),
      (__attribute__((address_space(3))) void*)(l), 16, 0, 0);
}

// ---------------- fp32 -> bf16 conversion (vectorized) ----------------
__global__ __launch_bounds__(256) void k_cvt(const float* __restrict__ in,
                                             __bf16* __restrict__ out, long n) {
  long i = (long)blockIdx.x * 256 + threadIdx.x;
  long stride = (long)gridDim.x * 256;
  for (long e = i * 8; e < n; e += stride * 8) {
    float4 v0 = *(const float4*)(in + e);
    float4 v1 = *(const float4*)(in + e + 4);
    bf16x8 o;
    o[0] = (__bf16)v0.x; o[1] = (__bf16)v0.y; o[2] = (__bf16)v0.z; o[3] = (__bf16)v0.w;
    o[4] = (__bf16)v1.x; o[5] = (__bf16)v1.y; o[6] = (__bf16)v1.z; o[7] = (__bf16)v1.w;
    *(bf16x8*)(out + e) = o;
  }
}

// ---------------- bf16 GEMM, C = A * B^T  (A: MxK, B: NxK, both K-contig) --
// m97-exact structure: 128x128 tile, BK=32, 4 waves (2x2), 16 KB single-
// buffered LDS, 2 __syncthreads per K-tile, NO inline waitcnt/sched_barrier/
// setprio (round-5 post-mortem: explicit pinning defeats the compiler's
// fine-grained lgkmcnt interleave of ds_read drain with MFMA issue — m141).
// Many blocks/CU (16 KB LDS) provide cross-block overlap of the barrier
// drain (the m97 mechanism, verified 874-912 TF).
// Fixes vs round-2's 694 TF version of this structure:
//  - 16B-chunk XOR swizzle (chunk ^= (row>>1)&3) via pre-swizzled global
//    source + same involution on read: 0 bank conflicts (measured round 5).
//  - staging pointers precomputed per thread, incremented by 32 elems/tile
//    (round-2 recomputed 64-bit addresses per tile -> VALUBusy 45%).
template <typename OutT>
__global__ __launch_bounds__(256) void k_gemm128(const __bf16* __restrict__ A,
                                                 const __bf16* __restrict__ B,
                                                 OutT* __restrict__ C,
                                                 int M, int N, int K) {
  __shared__ __bf16 As[128 * 32];  // 8 KB
  __shared__ __bf16 Bs[128 * 32];  // 8 KB
  const int t = threadIdx.x;
  const int l = t & 63;
  const int w = t >> 6;
  const int wr = w >> 1, wc = w & 1;
  const int lr = l & 15, lg = l >> 4;
  const int rsw = (lr >> 1) & 3;   // read-side chunk XOR ((row>>1)&3 == (lr>>1)&3)
  const int bm = blockIdx.y, bn = blockIdx.x;

  // staging: issue = 256 thr x 16B = 64 rows x 64B. thread t -> row t>>2,
  // source chunk (t&3)^((t>>3)&3)  (LDS lands linearly: LDS[row][t&3]).
  const int scol = (((t & 3) ^ ((t >> 3) & 3)) << 3);
  const __bf16* pa0 = A + (size_t)(bm * 128 + (t >> 2)) * K + scol;
  const __bf16* pa1 = pa0 + (size_t)64 * K;
  const __bf16* pb0 = B + (size_t)(bn * 128 + (t >> 2)) * K + scol;
  const __bf16* pb1 = pb0 + (size_t)64 * K;
  const int ldst = t * 8;          // linear LDS elem dest (wave base + lane*16B)

  // read bases (constant per thread; frag offsets are immediates)
  const int aoff = (wr * 64 + lr) * 32 + ((lg ^ rsw) * 8);
  const int boff = (wc * 64 + lr) * 32 + ((lg ^ rsw) * 8);

  f32x4 acc[4][4] = {};
  const int nt = K >> 5;

  for (int kt = 0; kt < nt; ++kt) {
    __syncthreads();               // prior tile's reads done (no-op first iter)
    gld_lds16(pa0, &As[ldst]);
    gld_lds16(pa1, &As[2048 + ldst]);
    gld_lds16(pb0, &Bs[ldst]);
    gld_lds16(pb1, &Bs[2048 + ldst]);
    pa0 += 32; pa1 += 32; pb0 += 32; pb1 += 32;
    __syncthreads();               // staged tile visible (drains vmcnt)

    bf16x8 a[4], b[4];
#pragma unroll
    for (int mi = 0; mi < 4; ++mi)
      a[mi] = *(const bf16x8*)&As[aoff + mi * 512];
#pragma unroll
    for (int ni = 0; ni < 4; ++ni)
      b[ni] = *(const bf16x8*)&Bs[boff + ni * 512];
#pragma unroll
    for (int mi = 0; mi < 4; ++mi)
#pragma unroll
      for (int ni = 0; ni < 4; ++ni)
        acc[mi][ni] = __builtin_amdgcn_mfma_f32_16x16x32_bf16(a[mi], b[ni], acc[mi][ni], 0, 0, 0);
  }

  const int row0 = bm * 128 + wr * 64;
  const int col0 = bn * 128 + wc * 64;
#pragma unroll
  for (int mi = 0; mi < 4; ++mi)
#pragma unroll
    for (int ni = 0; ni < 4; ++ni)
#pragma unroll
      for (int r = 0; r < 4; ++r)
        C[(size_t)(row0 + mi * 16 + lg * 4 + r) * N + (col0 + ni * 16 + lr)] =
            (OutT)acc[mi][ni][r];
}

// ---------------- fused RoPE + RMSNorm (in-place on Q and K regions) -------
__global__ __launch_bounds__(256) void k_rope_norm(__bf16* __restrict__ qkv,
                                                   const float* __restrict__ cosT,
                                                   const float* __restrict__ sinT) {
  const int task = blockIdx.x * 4 + (threadIdx.x >> 6);
  const int l = threadIdx.x & 63;
  const int m = task / 40;          // row in [0, 4096)
  const int h = task - m * 40;      // 0..31 = Q heads, 32..39 = K heads
  const int s = m & (SEQ - 1);
  const bool isQ = h < 32;
  const int col = isQ ? h * 128 : 4096 + (h - 32) * 128;
  __bf16* p = qkv + (size_t)m * QKVN + col + l * 2;
  float e = (float)p[0], o = (float)p[1];
  float c = cosT[s * 64 + l], sn = sinT[s * 64 + l];
  float e2 = e * c - o * sn;
  float o2 = e * sn + o * c;
  float ss = e2 * e2 + o2 * o2;
#pragma unroll
  for (int off = 32; off > 0; off >>= 1) ss += __shfl_xor(ss, off);
  float r = rsqrtf(ss * (1.0f / 128.0f) + 1e-5f);
  if (isQ) r *= 0.08838834764831845f;  // fold 1/sqrt(HEAD_DIM) into Q
  p[0] = (__bf16)(e2 * r);
  p[1] = (__bf16)(o2 * r);
}

// ---------------- V transpose: qkv V region (b,s,g,d) -> vt (b,g,d,s) ------
__global__ __launch_bounds__(256) void k_transpose_v(const __bf16* __restrict__ qkv,
                                                     __bf16* __restrict__ vt) {
  __shared__ __bf16 tile[64][136];  // padded row, no bank conflicts
  const int t = threadIdx.x;
  const int st = blockIdx.x, bg = blockIdx.y;
  const int b = bg >> 3, g = bg & 7;
  const int s0 = st * 64;
#pragma unroll
  for (int p = 0; p < 4; ++p) {
    int row = p * 16 + (t >> 4);
    int co = (t & 15) * 8;
    *(bf16x8*)&tile[row][co] =
        *(const bf16x8*)&qkv[(size_t)(b * SEQ + s0 + row) * QKVN + 5120 + g * 128 + co];
  }
  __syncthreads();
#pragma unroll
  for (int p = 0; p < 4; ++p) {
    int d = p * 32 + (t >> 3);
    int so = (t & 7) * 8;
    bf16x8 v;
#pragma unroll
    for (int j = 0; j < 8; ++j) v[j] = tile[so + j][d];
    *(bf16x8*)&vt[((size_t)bg * 128 + d) * SEQ + s0 + so] = v;
  }
}

// ---------------- causal flash attention (GQA) ------------------------------
__global__ __launch_bounds__(256) void k_flash(const __bf16* __restrict__ qkv,
                                               const __bf16* __restrict__ vt,
                                               __bf16* __restrict__ attno) {
  __shared__ __bf16 Ks[64 * 128];   // [kv][d], swizzled
  __shared__ __bf16 Vs[128 * 64];   // [d][kv], swizzled
  __shared__ __bf16 Ps[4][16 * 64]; // per-wave [q][kv], swizzled
  const int t = threadIdx.x, w = t >> 6, l = t & 63;
  const int lr = l & 15, lg = l >> 4;
  const int bh = blockIdx.y;        // b*32 + h
  const int b = bh >> 5, h = bh & 31, g = h >> 2;
  const int qt0 = blockIdx.x, qt1 = 31 - (int)blockIdx.x;

  const __bf16* Kb = qkv + 4096 + (size_t)(b * SEQ) * QKVN + g * 128;
  const __bf16* Vtb = vt + ((size_t)(b * 8 + g)) * 128 * SEQ;
  const int wbase = (t & ~63) * 8;
  const int sw = lr & 7;            // read-side XOR (row&7 == lr&7 everywhere)

  for (int pass = 0; pass < 2; ++pass) {
    const int qt = (pass == 0) ? qt0 : qt1;

    const __bf16* Qb = qkv + (size_t)(b * SEQ + qt * 64 + w * 16 + lr) * QKVN + h * 128;
    bf16x8 qf[4];
#pragma unroll
    for (int kk = 0; kk < 4; ++kk) qf[kk] = *(const bf16x8*)&Qb[kk * 32 + lg * 8];

    f32x4 oacc[8] = {};
    float mrow[4], lsum[4];
#pragma unroll
    for (int r = 0; r < 4; ++r) { mrow[r] = -1e30f; lsum[r] = 0.f; }

    for (int kt = 0; kt <= qt; ++kt) {
      const int kv0 = kt * 64;
#pragma unroll
      for (int i = 0; i < 4; ++i) {
        int e = i * 256 + t;
        gld_lds16(Kb + (size_t)(kv0 + (e >> 4)) * QKVN + ((e & 15) ^ ((e >> 4) & 7)) * 8,
                  &Ks[i * 2048 + wbase]);
      }
#pragma unroll
      for (int i = 0; i < 4; ++i) {
        int e = i * 256 + t;
        gld_lds16(Vtb + (size_t)(e >> 3) * SEQ + kv0 + (((e & 7) ^ ((e >> 3) & 7))) * 8,
                  &Vs[i * 2048 + wbase]);
      }
      __syncthreads();

      // S = Q K^T
      f32x4 sc[4] = {};
#pragma unroll
      for (int kk = 0; kk < 4; ++kk)
#pragma unroll
        for (int n = 0; n < 4; ++n) {
          bf16x8 kf = *(const bf16x8*)&Ks[(n * 16 + lr) * 128 + ((kk * 4 + lg) ^ sw) * 8];
          sc[n] = __builtin_amdgcn_mfma_f32_16x16x32_bf16(qf[kk], kf, sc[n], 0, 0, 0);
        }

      if (kt == qt) {  // diagonal tile: causal mask
#pragma unroll
        for (int n = 0; n < 4; ++n)
#pragma unroll
          for (int r = 0; r < 4; ++r)
            if (n * 16 + lr > w * 16 + lg * 4 + r) sc[n][r] = -1e30f;
      }

      // online softmax (row = lg*4 + r; 16 lanes hold the cols)
#pragma unroll
      for (int r = 0; r < 4; ++r) {
        float pm = fmaxf(fmaxf(sc[0][r], sc[1][r]), fmaxf(sc[2][r], sc[3][r]));
#pragma unroll
        for (int off = 8; off > 0; off >>= 1) pm = fmaxf(pm, __shfl_xor(pm, off));
        float mn = fmaxf(mrow[r], pm);
        float corr = __expf(mrow[r] - mn);
        mrow[r] = mn;
        float ps = 0.f;
#pragma unroll
        for (int n = 0; n < 4; ++n) { sc[n][r] = __expf(sc[n][r] - mn); ps += sc[n][r]; }
#pragma unroll
        for (int off = 8; off > 0; off >>= 1) ps += __shfl_xor(ps, off);
        lsum[r] = lsum[r] * corr + ps;
#pragma unroll
        for (int dn = 0; dn < 8; ++dn) oacc[dn][r] *= corr;
      }

      // P -> LDS (swizzled)
#pragma unroll
      for (int n = 0; n < 4; ++n)
#pragma unroll
        for (int r = 0; r < 4; ++r) {
          int row = lg * 4 + r;
          Ps[w][row * 64 + (((n * 2 + (lr >> 3)) ^ (row & 7)) * 8) + (lr & 7)] = (__bf16)sc[n][r];
        }

      // O += P V
#pragma unroll
      for (int ks = 0; ks < 2; ++ks) {
        bf16x8 pf = *(const bf16x8*)&Ps[w][lr * 64 + ((ks * 4 + lg) ^ sw) * 8];
#pragma unroll
        for (int dn = 0; dn < 8; ++dn) {
          bf16x8 vf = *(const bf16x8*)&Vs[(dn * 16 + lr) * 64 + ((ks * 4 + lg) ^ sw) * 8];
          oacc[dn] = __builtin_amdgcn_mfma_f32_16x16x32_bf16(pf, vf, oacc[dn], 0, 0, 0);
        }
      }
      __syncthreads();
    }

    __bf16* Ob = attno + (size_t)(b * SEQ + qt * 64 + w * 16) * DIMSZ + h * 128;
#pragma unroll
    for (int dn = 0; dn < 8; ++dn)
#pragma unroll
      for (int r = 0; r < 4; ++r)
        Ob[(size_t)(lg * 4 + r) * DIMSZ + dn * 16 + lr] = (__bf16)(oacc[dn][r] / lsum[r]);
  }
}

// ---------------- host launcher --------------------------------------------
extern "C" void kernel_launch(void* const* d_in, const int* in_sizes, int n_in,
                              void* d_out, int out_size, void* d_ws, size_t ws_size,
                              hipStream_t stream) {
  const float* x    = (const float*)d_in[0];
  const float* wq   = (const float*)d_in[1];
  const float* wk   = (const float*)d_in[2];
  const float* wv   = (const float*)d_in[3];
  const float* wo   = (const float*)d_in[4];
  const float* cosT = (const float*)d_in[5];
  const float* sinT = (const float*)d_in[6];
  // d_in[7] (mask) implemented as causal; d_in[8] (start_pos) == 0.

  char* ws = (char*)d_ws;
  __bf16* xb    = (__bf16*)(ws);                    // 4096x4096        (32 MiB)
  __bf16* wqkvb = (__bf16*)(ws + 33554432);         // 6144x4096        (48 MiB)
  __bf16* qkvb  = (__bf16*)(ws + 83886080);         // 4096x6144        (48 MiB)
  __bf16* wob   = (__bf16*)(ws + 134217728);        // 4096x4096        (32 MiB)
  __bf16* vt    = (__bf16*)(ws + 167772160);        // 16x128x2048      ( 8 MiB)
  __bf16* attno = (__bf16*)(ws + 176160768);        // 4096x4096        (32 MiB)
  float* out = (float*)d_out;

  // fp32 -> bf16 conversions (wq/wk/wv concatenated into one 6144x4096 weight)
  k_cvt<<<8192, 256, 0, stream>>>(x, xb, 16777216L);
  k_cvt<<<8192, 256, 0, stream>>>(wq, wqkvb, 16777216L);
  k_cvt<<<2048, 256, 0, stream>>>(wk, wqkvb + 16777216, 4194304L);
  k_cvt<<<2048, 256, 0, stream>>>(wv, wqkvb + 20971520, 4194304L);
  k_cvt<<<8192, 256, 0, stream>>>(wo, wob, 16777216L);

  // QKV projection: M=4096, N=6144 -> grid (48, 32), bn fastest
  k_gemm128<__bf16><<<dim3(48, 32), 256, 0, stream>>>(xb, wqkvb, qkvb, 4096, QKVN, 4096);
  // RoPE + RMSNorm on Q,K (in place), attention scale folded into Q
  k_rope_norm<<<40960, 256, 0, stream>>>(qkvb, cosT, sinT);
  // V -> V^T for contiguous PV operand reads
  k_transpose_v<<<dim3(32, 16), 256, 0, stream>>>(qkvb, vt);
  // causal GQA flash attention (paired q-tiles for balance)
  k_flash<<<dim3(16, 64), 256, 0, stream>>>(qkvb, vt, attno);
  // output projection: M=4096, N=4096 -> grid (32, 32)
  k_gemm128<float><<<dim3(32, 32), 256, 0, stream>>>(attno, wob, out, 4096, DIMSZ, 4096);
}

// Round 7
// 675.074 us; speedup vs baseline: 1.0675x; 1.0675x over previous
//
#include <hip/hip_runtime.h>
#include <hip/hip_bf16.h>
#include <stdint.h>

#define SEQ 2048
#define DIMSZ 4096
#define QKVN 6144   // 4096 Q + 1024 K + 1024 V

typedef __attribute__((ext_vector_type(8))) __bf16 bf16x8;
typedef __attribute__((ext_vector_type(4))) float f32x4;

// async global->LDS, 16B per lane; dest = wave-uniform base + lane*16
static __device__ __forceinline__ void gld_lds16(const void* g, void* l) {
  __builtin_amdgcn_global_load_lds(
      (__attribute__((address_space(1))) void*)(g),
      (__attribute__((address_space(3))) void*)(l), 16, 0, 0);
}

// ---------------- fp32 -> bf16 conversion (vectorized) ----------------
__global__ __launch_bounds__(256) void k_cvt(const float* __restrict__ in,
                                             __bf16* __restrict__ out, long n) {
  long i = (long)blockIdx.x * 256 + threadIdx.x;
  long stride = (long)gridDim.x * 256;
  for (long e = i * 8; e < n; e += stride * 8) {
    float4 v0 = *(const float4*)(in + e);
    float4 v1 = *(const float4*)(in + e + 4);
    bf16x8 o;
    o[0] = (__bf16)v0.x; o[1] = (__bf16)v0.y; o[2] = (__bf16)v0.z; o[3] = (__bf16)v0.w;
    o[4] = (__bf16)v1.x; o[5] = (__bf16)v1.y; o[6] = (__bf16)v1.z; o[7] = (__bf16)v1.w;
    *(bf16x8*)(out + e) = o;
  }
}

// ---------------- bf16 GEMM, C = A * B^T  (A: MxK, B: NxK, both K-contig) --
// 128x128 tile, BK=32, 4 waves (2x2). ROUND-7 CHANGE: 3 LDS buffers,
// 2-tile-ahead prefetch, counted vmcnt(8) — never 0 in the loop.
//   iter t: STAGE tile t+2 -> buf[(t+2)%3]   (freed at end of iter t-1;
//                                             disjoint from both read bufs ->
//                                             no LDS write/read race)
//           s_waitcnt vmcnt(8)               (tiles t+1,t+2 = 8 loads remain;
//                                             tile t's loads, issued 2 iters
//                                             (~5400 cy) ago, retired: wait
//                                             is ~free vs the old ~900 cy
//                                             per-tile vmcnt(0) drain)
//           s_barrier                        (cross-wave visibility; every
//                                             wave verified its OWN 4 loads)
//           ds_read frags + 16 MFMA          (compiler-scheduled fine-grained
//                                             lgkmcnt — no pinning, m141)
//           s_barrier                        (reads done before next iter
//                                             stages into buf[t%3])
// Tail: stage clamped duplicate of last tile into the free buffer to keep
// the per-iter load count (and vmcnt arithmetic) uniform.
// T2 swizzle: 16B chunk ^= (row>>1)&3, pre-swizzled global source, same
// involution on read (0 conflicts, measured rounds 5/6).
template <typename OutT>
__global__ __launch_bounds__(256, 3) void k_gemm128(const __bf16* __restrict__ A,
                                                    const __bf16* __restrict__ B,
                                                    OutT* __restrict__ C,
                                                    int M, int N, int K) {
  __shared__ __bf16 As[3][128 * 32];  // 24 KB
  __shared__ __bf16 Bs[3][128 * 32];  // 24 KB
  const int t = threadIdx.x;
  const int l = t & 63;
  const int w = t >> 6;
  const int wr = w >> 1, wc = w & 1;
  const int lr = l & 15, lg = l >> 4;
  const int rsw = (lr >> 1) & 3;   // read-side chunk XOR ((row>>1)&3 == (lr>>1)&3)
  const int bm = blockIdx.y, bn = blockIdx.x;

  // staging: issue = 256 thr x 16B = 64 rows x 64B. thread t -> row t>>2,
  // source chunk (t&3)^((t>>3)&3)  (LDS lands linearly: LDS[row][t&3]).
  const int scol = (((t & 3) ^ ((t >> 3) & 3)) << 3);
  const __bf16* pa0 = A + (size_t)(bm * 128 + (t >> 2)) * K + scol;
  const __bf16* pa1 = pa0 + (size_t)64 * K;
  const __bf16* pb0 = B + (size_t)(bn * 128 + (t >> 2)) * K + scol;
  const __bf16* pb1 = pb0 + (size_t)64 * K;
  const int ldst = t * 8;          // linear LDS elem dest (wave base + lane*16B)

  const int aoff = (wr * 64 + lr) * 32 + ((lg ^ rsw) * 8);
  const int boff = (wc * 64 + lr) * 32 + ((lg ^ rsw) * 8);

  f32x4 acc[4][4] = {};
  const int nt = K >> 5;

  // prologue: stage tiles 0 and 1 (8 loads in flight)
  gld_lds16(pa0, &As[0][ldst]);       gld_lds16(pa1, &As[0][2048 + ldst]);
  gld_lds16(pb0, &Bs[0][ldst]);       gld_lds16(pb1, &Bs[0][2048 + ldst]);
  gld_lds16(pa0 + 32, &As[1][ldst]);  gld_lds16(pa1 + 32, &As[1][2048 + ldst]);
  gld_lds16(pb0 + 32, &Bs[1][ldst]);  gld_lds16(pb1 + 32, &Bs[1][2048 + ldst]);

  int rb = 0, sb = 2;
  for (int kt = 0; kt < nt; ++kt) {
    // stage tile kt+2 (clamped at tail; dest buffer is free either way)
    const int kc = ((kt + 2 < nt) ? kt + 2 : nt - 1) << 5;
    gld_lds16(pa0 + kc, &As[sb][ldst]);
    gld_lds16(pa1 + kc, &As[sb][2048 + ldst]);
    gld_lds16(pb0 + kc, &Bs[sb][ldst]);
    gld_lds16(pb1 + kc, &Bs[sb][2048 + ldst]);

    asm volatile("s_waitcnt vmcnt(8)" ::: "memory");  // tile kt landed (own)
    __builtin_amdgcn_s_barrier();                     // ... for ALL waves
    asm volatile("" ::: "memory");

    bf16x8 a[4], b[4];
#pragma unroll
    for (int mi = 0; mi < 4; ++mi)
      a[mi] = *(const bf16x8*)&As[rb][aoff + mi * 512];
#pragma unroll
    for (int ni = 0; ni < 4; ++ni)
      b[ni] = *(const bf16x8*)&Bs[rb][boff + ni * 512];
#pragma unroll
    for (int mi = 0; mi < 4; ++mi)
#pragma unroll
      for (int ni = 0; ni < 4; ++ni)
        acc[mi][ni] = __builtin_amdgcn_mfma_f32_16x16x32_bf16(a[mi], b[ni], acc[mi][ni], 0, 0, 0);

    asm volatile("" ::: "memory");
    __builtin_amdgcn_s_barrier();   // reads done before buf[rb] is restaged
    rb = (rb == 2) ? 0 : rb + 1;
    sb = (sb == 2) ? 0 : sb + 1;
  }

  const int row0 = bm * 128 + wr * 64;
  const int col0 = bn * 128 + wc * 64;
#pragma unroll
  for (int mi = 0; mi < 4; ++mi)
#pragma unroll
    for (int ni = 0; ni < 4; ++ni)
#pragma unroll
      for (int r = 0; r < 4; ++r)
        C[(size_t)(row0 + mi * 16 + lg * 4 + r) * N + (col0 + ni * 16 + lr)] =
            (OutT)acc[mi][ni][r];
}

// ---------------- fused RoPE + RMSNorm (in-place on Q and K regions) -------
__global__ __launch_bounds__(256) void k_rope_norm(__bf16* __restrict__ qkv,
                                                   const float* __restrict__ cosT,
                                                   const float* __restrict__ sinT) {
  const int task = blockIdx.x * 4 + (threadIdx.x >> 6);
  const int l = threadIdx.x & 63;
  const int m = task / 40;          // row in [0, 4096)
  const int h = task - m * 40;      // 0..31 = Q heads, 32..39 = K heads
  const int s = m & (SEQ - 1);
  const bool isQ = h < 32;
  const int col = isQ ? h * 128 : 4096 + (h - 32) * 128;
  __bf16* p = qkv + (size_t)m * QKVN + col + l * 2;
  float e = (float)p[0], o = (float)p[1];
  float c = cosT[s * 64 + l], sn = sinT[s * 64 + l];
  float e2 = e * c - o * sn;
  float o2 = e * sn + o * c;
  float ss = e2 * e2 + o2 * o2;
#pragma unroll
  for (int off = 32; off > 0; off >>= 1) ss += __shfl_xor(ss, off);
  float r = rsqrtf(ss * (1.0f / 128.0f) + 1e-5f);
  if (isQ) r *= 0.08838834764831845f;  // fold 1/sqrt(HEAD_DIM) into Q
  p[0] = (__bf16)(e2 * r);
  p[1] = (__bf16)(o2 * r);
}

// ---------------- V transpose: qkv V region (b,s,g,d) -> vt (b,g,d,s) ------
__global__ __launch_bounds__(256) void k_transpose_v(const __bf16* __restrict__ qkv,
                                                     __bf16* __restrict__ vt) {
  __shared__ __bf16 tile[64][136];  // padded row, no bank conflicts
  const int t = threadIdx.x;
  const int st = blockIdx.x, bg = blockIdx.y;
  const int b = bg >> 3, g = bg & 7;
  const int s0 = st * 64;
#pragma unroll
  for (int p = 0; p < 4; ++p) {
    int row = p * 16 + (t >> 4);
    int co = (t & 15) * 8;
    *(bf16x8*)&tile[row][co] =
        *(const bf16x8*)&qkv[(size_t)(b * SEQ + s0 + row) * QKVN + 5120 + g * 128 + co];
  }
  __syncthreads();
#pragma unroll
  for (int p = 0; p < 4; ++p) {
    int d = p * 32 + (t >> 3);
    int so = (t & 7) * 8;
    bf16x8 v;
#pragma unroll
    for (int j = 0; j < 8; ++j) v[j] = tile[so + j][d];
    *(bf16x8*)&vt[((size_t)bg * 128 + d) * SEQ + s0 + so] = v;
  }
}

// ---------------- causal flash attention (GQA) ------------------------------
__global__ __launch_bounds__(256) void k_flash(const __bf16* __restrict__ qkv,
                                               const __bf16* __restrict__ vt,
                                               __bf16* __restrict__ attno) {
  __shared__ __bf16 Ks[64 * 128];   // [kv][d], swizzled
  __shared__ __bf16 Vs[128 * 64];   // [d][kv], swizzled
  __shared__ __bf16 Ps[4][16 * 64]; // per-wave [q][kv], swizzled
  const int t = threadIdx.x, w = t >> 6, l = t & 63;
  const int lr = l & 15, lg = l >> 4;
  const int bh = blockIdx.y;        // b*32 + h
  const int b = bh >> 5, h = bh & 31, g = h >> 2;
  const int qt0 = blockIdx.x, qt1 = 31 - (int)blockIdx.x;

  const __bf16* Kb = qkv + 4096 + (size_t)(b * SEQ) * QKVN + g * 128;
  const __bf16* Vtb = vt + ((size_t)(b * 8 + g)) * 128 * SEQ;
  const int wbase = (t & ~63) * 8;
  const int sw = lr & 7;            // read-side XOR (row&7 == lr&7 everywhere)

  for (int pass = 0; pass < 2; ++pass) {
    const int qt = (pass == 0) ? qt0 : qt1;

    const __bf16* Qb = qkv + (size_t)(b * SEQ + qt * 64 + w * 16 + lr) * QKVN + h * 128;
    bf16x8 qf[4];
#pragma unroll
    for (int kk = 0; kk < 4; ++kk) qf[kk] = *(const bf16x8*)&Qb[kk * 32 + lg * 8];

    f32x4 oacc[8] = {};
    float mrow[4], lsum[4];
#pragma unroll
    for (int r = 0; r < 4; ++r) { mrow[r] = -1e30f; lsum[r] = 0.f; }

    for (int kt = 0; kt <= qt; ++kt) {
      const int kv0 = kt * 64;
#pragma unroll
      for (int i = 0; i < 4; ++i) {
        int e = i * 256 + t;
        gld_lds16(Kb + (size_t)(kv0 + (e >> 4)) * QKVN + ((e & 15) ^ ((e >> 4) & 7)) * 8,
                  &Ks[i * 2048 + wbase]);
      }
#pragma unroll
      for (int i = 0; i < 4; ++i) {
        int e = i * 256 + t;
        gld_lds16(Vtb + (size_t)(e >> 3) * SEQ + kv0 + (((e & 7) ^ ((e >> 3) & 7))) * 8,
                  &Vs[i * 2048 + wbase]);
      }
      __syncthreads();

      // S = Q K^T
      f32x4 sc[4] = {};
#pragma unroll
      for (int kk = 0; kk < 4; ++kk)
#pragma unroll
        for (int n = 0; n < 4; ++n) {
          bf16x8 kf = *(const bf16x8*)&Ks[(n * 16 + lr) * 128 + ((kk * 4 + lg) ^ sw) * 8];
          sc[n] = __builtin_amdgcn_mfma_f32_16x16x32_bf16(qf[kk], kf, sc[n], 0, 0, 0);
        }

      if (kt == qt) {  // diagonal tile: causal mask
#pragma unroll
        for (int n = 0; n < 4; ++n)
#pragma unroll
          for (int r = 0; r < 4; ++r)
            if (n * 16 + lr > w * 16 + lg * 4 + r) sc[n][r] = -1e30f;
      }

      // online softmax (row = lg*4 + r; 16 lanes hold the cols)
#pragma unroll
      for (int r = 0; r < 4; ++r) {
        float pm = fmaxf(fmaxf(sc[0][r], sc[1][r]), fmaxf(sc[2][r], sc[3][r]));
#pragma unroll
        for (int off = 8; off > 0; off >>= 1) pm = fmaxf(pm, __shfl_xor(pm, off));
        float mn = fmaxf(mrow[r], pm);
        float corr = __expf(mrow[r] - mn);
        mrow[r] = mn;
        float ps = 0.f;
#pragma unroll
        for (int n = 0; n < 4; ++n) { sc[n][r] = __expf(sc[n][r] - mn); ps += sc[n][r]; }
#pragma unroll
        for (int off = 8; off > 0; off >>= 1) ps += __shfl_xor(ps, off);
        lsum[r] = lsum[r] * corr + ps;
#pragma unroll
        for (int dn = 0; dn < 8; ++dn) oacc[dn][r] *= corr;
      }

      // P -> LDS (swizzled)
#pragma unroll
      for (int n = 0; n < 4; ++n)
#pragma unroll
        for (int r = 0; r < 4; ++r) {
          int row = lg * 4 + r;
          Ps[w][row * 64 + (((n * 2 + (lr >> 3)) ^ (row & 7)) * 8) + (lr & 7)] = (__bf16)sc[n][r];
        }

      // O += P V
#pragma unroll
      for (int ks = 0; ks < 2; ++ks) {
        bf16x8 pf = *(const bf16x8*)&Ps[w][lr * 64 + ((ks * 4 + lg) ^ sw) * 8];
#pragma unroll
        for (int dn = 0; dn < 8; ++dn) {
          bf16x8 vf = *(const bf16x8*)&Vs[(dn * 16 + lr) * 64 + ((ks * 4 + lg) ^ sw) * 8];
          oacc[dn] = __builtin_amdgcn_mfma_f32_16x16x32_bf16(pf, vf, oacc[dn], 0, 0, 0);
        }
      }
      __syncthreads();
    }

    __bf16* Ob = attno + (size_t)(b * SEQ + qt * 64 + w * 16) * DIMSZ + h * 128;
#pragma unroll
    for (int dn = 0; dn < 8; ++dn)
#pragma unroll
      for (int r = 0; r < 4; ++r)
        Ob[(size_t)(lg * 4 + r) * DIMSZ + dn * 16 + lr] = (__bf16)(oacc[dn][r] / lsum[r]);
  }
}

// ---------------- host launcher --------------------------------------------
extern "C" void kernel_launch(void* const* d_in, const int* in_sizes, int n_in,
                              void* d_out, int out_size, void* d_ws, size_t ws_size,
                              hipStream_t stream) {
  const float* x    = (const float*)d_in[0];
  const float* wq   = (const float*)d_in[1];
  const float* wk   = (const float*)d_in[2];
  const float* wv   = (const float*)d_in[3];
  const float* wo   = (const float*)d_in[4];
  const float* cosT = (const float*)d_in[5];
  const float* sinT = (const float*)d_in[6];
  // d_in[7] (mask) implemented as causal; d_in[8] (start_pos) == 0.

  char* ws = (char*)d_ws;
  __bf16* xb    = (__bf16*)(ws);                    // 4096x4096        (32 MiB)
  __bf16* wqkvb = (__bf16*)(ws + 33554432);         // 6144x4096        (48 MiB)
  __bf16* qkvb  = (__bf16*)(ws + 83886080);         // 4096x6144        (48 MiB)
  __bf16* wob   = (__bf16*)(ws + 134217728);        // 4096x4096        (32 MiB)
  __bf16* vt    = (__bf16*)(ws + 167772160);        // 16x128x2048      ( 8 MiB)
  __bf16* attno = (__bf16*)(ws + 176160768);        // 4096x4096        (32 MiB)
  float* out = (float*)d_out;

  // fp32 -> bf16 conversions (wq/wk/wv concatenated into one 6144x4096 weight)
  k_cvt<<<8192, 256, 0, stream>>>(x, xb, 16777216L);
  k_cvt<<<8192, 256, 0, stream>>>(wq, wqkvb, 16777216L);
  k_cvt<<<2048, 256, 0, stream>>>(wk, wqkvb + 16777216, 4194304L);
  k_cvt<<<2048, 256, 0, stream>>>(wv, wqkvb + 20971520, 4194304L);
  k_cvt<<<8192, 256, 0, stream>>>(wo, wob, 16777216L);

  // QKV projection: M=4096, N=6144 -> grid (48, 32), bn fastest
  k_gemm128<__bf16><<<dim3(48, 32), 256, 0, stream>>>(xb, wqkvb, qkvb, 4096, QKVN, 4096);
  // RoPE + RMSNorm on Q,K (in place), attention scale folded into Q
  k_rope_norm<<<40960, 256, 0, stream>>>(qkvb, cosT, sinT);
  // V -> V^T for contiguous PV operand reads
  k_transpose_v<<<dim3(32, 16), 256, 0, stream>>>(qkvb, vt);
  // causal GQA flash attention (paired q-tiles for balance)
  k_flash<<<dim3(16, 64), 256, 0, stream>>>(qkvb, vt, attno);
  // output projection: M=4096, N=4096 -> grid (32, 32)
  k_gemm128<float><<<dim3(32, 32), 256, 0, stream>>>(attno, wob, out, 4096, DIMSZ, 4096);
}

// Round 8
// 630.993 us; speedup vs baseline: 1.1421x; 1.0699x over previous
//
#include <hip/hip_runtime.h>
#include <hip/hip_bf16.h>
#include <stdint.h>

#define SEQ 2048
#define DIMSZ 4096
#define QKVN 6144   // 4096 Q + 1024 K + 1024 V

typedef __attribute__((ext_vector_type(8))) __bf16 bf16x8;
typedef __attribute__((ext_vector_type(4))) float f32x4;

// async global->LDS, 16B per lane; dest = wave-uniform base + lane*16
static __device__ __forceinline__ void gld_lds16(const void* g, void* l) {
  __builtin_amdgcn_global_load_lds(
      (__attribute__((address_space(1))) void*)(g),
      (__attribute__((address_space(3))) void*)(l), 16, 0, 0);
}

static __device__ __forceinline__ void blockbar() {
  asm volatile("" ::: "memory");
  __builtin_amdgcn_s_barrier();
  asm volatile("" ::: "memory");
}

// ---------------- fp32 -> bf16 conversion (vectorized) ----------------
__global__ __launch_bounds__(256) void k_cvt(const float* __restrict__ in,
                                             __bf16* __restrict__ out, long n) {
  long i = (long)blockIdx.x * 256 + threadIdx.x;
  long stride = (long)gridDim.x * 256;
  for (long e = i * 8; e < n; e += stride * 8) {
    float4 v0 = *(const float4*)(in + e);
    float4 v1 = *(const float4*)(in + e + 4);
    bf16x8 o;
    o[0] = (__bf16)v0.x; o[1] = (__bf16)v0.y; o[2] = (__bf16)v0.z; o[3] = (__bf16)v0.w;
    o[4] = (__bf16)v1.x; o[5] = (__bf16)v1.y; o[6] = (__bf16)v1.z; o[7] = (__bf16)v1.w;
    *(bf16x8*)(out + e) = o;
  }
}

// ---------------- bf16 GEMM, C = A * B^T  (A: MxK, B: NxK, both K-contig) --
// m201-geometry port: 256x256 tile, BK=64, 512 thr (8 waves, 2M x 4N),
// 128 KiB LDS [2buf][2half][128x64]. 4 sub-phases per K-tile:
//   p0: ds_read a03+b01 (12 b128) | stage B-h0(T+1) | bar | 16 MFMA | bar
//   p1: ds_read b23 (4)           | stage B-h1(T+1) | bar | 16 MFMA | bar
//   p2: ds_read a47 (8, A's LAST) |  (no stage)     | bar | 16 MFMA | bar
//   p3: (no reads)                | stage A(T+2) x4 | bar | 16 MFMA |
//       s_waitcnt vmcnt(4) <- counted, never 0      | bar
// Staging-to-phase map is race-free by construction: A(T+2) shares tile T's
// buffer but is staged at p3, after A's last read (p2) + double barrier;
// B(T+1) goes to the other buffer. vmcnt(4) at the boundary retires B(T+1)
// (staged p0/p1, 2-3 phases to land); outstanding = A(T+2)'s 4 loads.
// No lgkmcnt/sched_barrier pinning (m141); compiler fine-schedules reads
// into MFMA. T2 swizzle: 16B chunk ^= row&7 via pre-swizzled global source
// (0 conflicts measured in rounds 5-7). T5 setprio around each MFMA cluster.
template <typename OutT>
__global__ __launch_bounds__(512) void k_gemm256(const __bf16* __restrict__ A,
                                                 const __bf16* __restrict__ B,
                                                 OutT* __restrict__ C,
                                                 int M, int N, int K) {
  __shared__ __align__(16) __bf16 As[2][2][128 * 64];  // 64 KiB
  __shared__ __align__(16) __bf16 Bs[2][2][128 * 64];  // 64 KiB
  const int t = threadIdx.x;
  const int l = t & 63;
  const int w = t >> 6;        // 0..7
  const int wm = w >> 2;       // 0..1 : C rows [wm*128, +128) == A half wm
  const int wn = w & 3;        // 0..3 : C cols [wn*64, +64)  == B half wn>>1
  const int lr = l & 15, lg = l >> 4;
  const int sw = lr & 7;       // read-side chunk XOR (row&7 == lr&7, rows %16)
  const int bm = blockIdx.y, bn = blockIdx.x;

  // staging: one gld_lds = 512 thr x 16B = 64 rows x 64 cols (8 chunks).
  // thread t -> row (t>>3), src chunk (t&7)^((t>>3)&7); LDS lands linearly.
  const int srow = t >> 3;
  const int scol = ((t & 7) ^ (srow & 7)) << 3;
  const __bf16* pa0 = A + (size_t)(bm * 256 +   0 + srow) * K + scol;
  const __bf16* pa1 = A + (size_t)(bm * 256 +  64 + srow) * K + scol;
  const __bf16* pa2 = A + (size_t)(bm * 256 + 128 + srow) * K + scol;
  const __bf16* pa3 = A + (size_t)(bm * 256 + 192 + srow) * K + scol;
  const __bf16* pb0 = B + (size_t)(bn * 256 +   0 + srow) * K + scol;
  const __bf16* pb1 = B + (size_t)(bn * 256 +  64 + srow) * K + scol;
  const __bf16* pb2 = B + (size_t)(bn * 256 + 128 + srow) * K + scol;
  const __bf16* pb3 = B + (size_t)(bn * 256 + 192 + srow) * K + scol;
  const int ldst = t * 8;      // elem dest within a half: issue base + t*16B

#define STAGE_A(buf, kc)                              \
  do {                                                \
    gld_lds16(pa0 + (kc), &As[buf][0][ldst]);         \
    gld_lds16(pa1 + (kc), &As[buf][0][4096 + ldst]);  \
    gld_lds16(pa2 + (kc), &As[buf][1][ldst]);         \
    gld_lds16(pa3 + (kc), &As[buf][1][4096 + ldst]);  \
  } while (0)
#define STAGE_B0(buf, kc)                             \
  do {                                                \
    gld_lds16(pb0 + (kc), &Bs[buf][0][ldst]);         \
    gld_lds16(pb1 + (kc), &Bs[buf][0][4096 + ldst]);  \
  } while (0)
#define STAGE_B1(buf, kc)                             \
  do {                                                \
    gld_lds16(pb2 + (kc), &Bs[buf][1][ldst]);         \
    gld_lds16(pb3 + (kc), &Bs[buf][1][4096 + ldst]);  \
  } while (0)

  // frag read offsets: logical chunk kk*4+lg, stored chunk ^= sw
  const int c0 = ((lg ^ sw) * 8);          // kk=0
  const int c1 = (((lg ^ sw) ^ 4) * 8);    // kk=1 (lg+4 == lg^4)
  const int aRow = lr;                     // + mi*16
  const int bRow = (wn & 1) * 64 + lr;     // + ni*16

  f32x4 acc[8][4] = {};
  const int nt = K >> 6;

  // prologue: A(0), B(0), A(1) = 12 loads; tile 0 complete at vmcnt(4)
  STAGE_A(0, 0);
  STAGE_B0(0, 0);
  STAGE_B1(0, 0);
  STAGE_A(1, (nt > 1 ? 64 : 0));
  asm volatile("s_waitcnt vmcnt(4)" ::: "memory");
  blockbar();

  for (int T = 0; T < nt; ++T) {
    const int cur = T & 1;
    const int kB = (T + 1 < nt ? T + 1 : nt - 1) << 6;
    const int kA = (T + 2 < nt ? T + 2 : nt - 1) << 6;
    bf16x8 a[4][2], b0[2][2], b1[2][2];

    // ---------- phase 0: a03 x b01 ----------
#pragma unroll
    for (int mi = 0; mi < 4; ++mi) {
      a[mi][0] = *(const bf16x8*)&As[cur][wm][(mi * 16 + aRow) * 64 + c0];
      a[mi][1] = *(const bf16x8*)&As[cur][wm][(mi * 16 + aRow) * 64 + c1];
    }
#pragma unroll
    for (int ni = 0; ni < 2; ++ni) {
      b0[ni][0] = *(const bf16x8*)&Bs[cur][wn >> 1][(ni * 16 + bRow) * 64 + c0];
      b0[ni][1] = *(const bf16x8*)&Bs[cur][wn >> 1][(ni * 16 + bRow) * 64 + c1];
    }
    STAGE_B0((T + 1) & 1, kB);
    blockbar();
    __builtin_amdgcn_s_setprio(1);
#pragma unroll
    for (int mi = 0; mi < 4; ++mi)
#pragma unroll
      for (int ni = 0; ni < 2; ++ni)
#pragma unroll
        for (int kk = 0; kk < 2; ++kk)
          acc[mi][ni] = __builtin_amdgcn_mfma_f32_16x16x32_bf16(a[mi][kk], b0[ni][kk], acc[mi][ni], 0, 0, 0);
    __builtin_amdgcn_s_setprio(0);
    blockbar();

    // ---------- phase 1: a03 x b23 ----------
#pragma unroll
    for (int ni = 0; ni < 2; ++ni) {
      b1[ni][0] = *(const bf16x8*)&Bs[cur][wn >> 1][((ni + 2) * 16 + bRow) * 64 + c0];
      b1[ni][1] = *(const bf16x8*)&Bs[cur][wn >> 1][((ni + 2) * 16 + bRow) * 64 + c1];
    }
    STAGE_B1((T + 1) & 1, kB);
    blockbar();
    __builtin_amdgcn_s_setprio(1);
#pragma unroll
    for (int mi = 0; mi < 4; ++mi)
#pragma unroll
      for (int ni = 0; ni < 2; ++ni)
#pragma unroll
        for (int kk = 0; kk < 2; ++kk)
          acc[mi][ni + 2] = __builtin_amdgcn_mfma_f32_16x16x32_bf16(a[mi][kk], b1[ni][kk], acc[mi][ni + 2], 0, 0, 0);
    __builtin_amdgcn_s_setprio(0);
    blockbar();

    // ---------- phase 2: a47 x b23 (A's last LDS read this tile) ----------
#pragma unroll
    for (int mi = 0; mi < 4; ++mi) {
      a[mi][0] = *(const bf16x8*)&As[cur][wm][((mi + 4) * 16 + aRow) * 64 + c0];
      a[mi][1] = *(const bf16x8*)&As[cur][wm][((mi + 4) * 16 + aRow) * 64 + c1];
    }
    blockbar();
    __builtin_amdgcn_s_setprio(1);
#pragma unroll
    for (int mi = 0; mi < 4; ++mi)
#pragma unroll
      for (int ni = 0; ni < 2; ++ni)
#pragma unroll
        for (int kk = 0; kk < 2; ++kk)
          acc[mi + 4][ni + 2] = __builtin_amdgcn_mfma_f32_16x16x32_bf16(a[mi][kk], b1[ni][kk], acc[mi + 4][ni + 2], 0, 0, 0);
    __builtin_amdgcn_s_setprio(0);
    blockbar();

    // ---------- phase 3: a47 x b01; stage A(T+2) into tile T's buffer ------
    STAGE_A(cur, kA);
    blockbar();
    __builtin_amdgcn_s_setprio(1);
#pragma unroll
    for (int mi = 0; mi < 4; ++mi)
#pragma unroll
      for (int ni = 0; ni < 2; ++ni)
#pragma unroll
        for (int kk = 0; kk < 2; ++kk)
          acc[mi + 4][ni] = __builtin_amdgcn_mfma_f32_16x16x32_bf16(a[mi][kk], b0[ni][kk], acc[mi + 4][ni], 0, 0, 0);
    __builtin_amdgcn_s_setprio(0);
    // tile boundary: retire B(T+1); keep A(T+2)'s 4 loads in flight
    asm volatile("s_waitcnt vmcnt(4)" ::: "memory");
    blockbar();
  }
#undef STAGE_A
#undef STAGE_B0
#undef STAGE_B1

  const int row0 = bm * 256 + wm * 128;
  const int col0 = bn * 256 + wn * 64;
#pragma unroll
  for (int mi = 0; mi < 8; ++mi)
#pragma unroll
    for (int ni = 0; ni < 4; ++ni)
#pragma unroll
      for (int r = 0; r < 4; ++r)
        C[(size_t)(row0 + mi * 16 + lg * 4 + r) * N + (col0 + ni * 16 + lr)] =
            (OutT)acc[mi][ni][r];
}

// ---------------- fused RoPE + RMSNorm (in-place on Q and K regions) -------
__global__ __launch_bounds__(256) void k_rope_norm(__bf16* __restrict__ qkv,
                                                   const float* __restrict__ cosT,
                                                   const float* __restrict__ sinT) {
  const int task = blockIdx.x * 4 + (threadIdx.x >> 6);
  const int l = threadIdx.x & 63;
  const int m = task / 40;          // row in [0, 4096)
  const int h = task - m * 40;      // 0..31 = Q heads, 32..39 = K heads
  const int s = m & (SEQ - 1);
  const bool isQ = h < 32;
  const int col = isQ ? h * 128 : 4096 + (h - 32) * 128;
  __bf16* p = qkv + (size_t)m * QKVN + col + l * 2;
  float e = (float)p[0], o = (float)p[1];
  float c = cosT[s * 64 + l], sn = sinT[s * 64 + l];
  float e2 = e * c - o * sn;
  float o2 = e * sn + o * c;
  float ss = e2 * e2 + o2 * o2;
#pragma unroll
  for (int off = 32; off > 0; off >>= 1) ss += __shfl_xor(ss, off);
  float r = rsqrtf(ss * (1.0f / 128.0f) + 1e-5f);
  if (isQ) r *= 0.08838834764831845f;  // fold 1/sqrt(HEAD_DIM) into Q
  p[0] = (__bf16)(e2 * r);
  p[1] = (__bf16)(o2 * r);
}

// ---------------- V transpose: qkv V region (b,s,g,d) -> vt (b,g,d,s) ------
__global__ __launch_bounds__(256) void k_transpose_v(const __bf16* __restrict__ qkv,
                                                     __bf16* __restrict__ vt) {
  __shared__ __bf16 tile[64][136];  // padded row, no bank conflicts
  const int t = threadIdx.x;
  const int st = blockIdx.x, bg = blockIdx.y;
  const int b = bg >> 3, g = bg & 7;
  const int s0 = st * 64;
#pragma unroll
  for (int p = 0; p < 4; ++p) {
    int row = p * 16 + (t >> 4);
    int co = (t & 15) * 8;
    *(bf16x8*)&tile[row][co] =
        *(const bf16x8*)&qkv[(size_t)(b * SEQ + s0 + row) * QKVN + 5120 + g * 128 + co];
  }
  __syncthreads();
#pragma unroll
  for (int p = 0; p < 4; ++p) {
    int d = p * 32 + (t >> 3);
    int so = (t & 7) * 8;
    bf16x8 v;
#pragma unroll
    for (int j = 0; j < 8; ++j) v[j] = tile[so + j][d];
    *(bf16x8*)&vt[((size_t)bg * 128 + d) * SEQ + s0 + so] = v;
  }
}

// ---------------- causal flash attention (GQA) ------------------------------
__global__ __launch_bounds__(256) void k_flash(const __bf16* __restrict__ qkv,
                                               const __bf16* __restrict__ vt,
                                               __bf16* __restrict__ attno) {
  __shared__ __bf16 Ks[64 * 128];   // [kv][d], swizzled
  __shared__ __bf16 Vs[128 * 64];   // [d][kv], swizzled
  __shared__ __bf16 Ps[4][16 * 64]; // per-wave [q][kv], swizzled
  const int t = threadIdx.x, w = t >> 6, l = t & 63;
  const int lr = l & 15, lg = l >> 4;
  const int bh = blockIdx.y;        // b*32 + h
  const int b = bh >> 5, h = bh & 31, g = h >> 2;
  const int qt0 = blockIdx.x, qt1 = 31 - (int)blockIdx.x;

  const __bf16* Kb = qkv + 4096 + (size_t)(b * SEQ) * QKVN + g * 128;
  const __bf16* Vtb = vt + ((size_t)(b * 8 + g)) * 128 * SEQ;
  const int wbase = (t & ~63) * 8;
  const int sw = lr & 7;            // read-side XOR (row&7 == lr&7 everywhere)

  for (int pass = 0; pass < 2; ++pass) {
    const int qt = (pass == 0) ? qt0 : qt1;

    const __bf16* Qb = qkv + (size_t)(b * SEQ + qt * 64 + w * 16 + lr) * QKVN + h * 128;
    bf16x8 qf[4];
#pragma unroll
    for (int kk = 0; kk < 4; ++kk) qf[kk] = *(const bf16x8*)&Qb[kk * 32 + lg * 8];

    f32x4 oacc[8] = {};
    float mrow[4], lsum[4];
#pragma unroll
    for (int r = 0; r < 4; ++r) { mrow[r] = -1e30f; lsum[r] = 0.f; }

    for (int kt = 0; kt <= qt; ++kt) {
      const int kv0 = kt * 64;
#pragma unroll
      for (int i = 0; i < 4; ++i) {
        int e = i * 256 + t;
        gld_lds16(Kb + (size_t)(kv0 + (e >> 4)) * QKVN + ((e & 15) ^ ((e >> 4) & 7)) * 8,
                  &Ks[i * 2048 + wbase]);
      }
#pragma unroll
      for (int i = 0; i < 4; ++i) {
        int e = i * 256 + t;
        gld_lds16(Vtb + (size_t)(e >> 3) * SEQ + kv0 + (((e & 7) ^ ((e >> 3) & 7))) * 8,
                  &Vs[i * 2048 + wbase]);
      }
      __syncthreads();

      // S = Q K^T
      f32x4 sc[4] = {};
#pragma unroll
      for (int kk = 0; kk < 4; ++kk)
#pragma unroll
        for (int n = 0; n < 4; ++n) {
          bf16x8 kf = *(const bf16x8*)&Ks[(n * 16 + lr) * 128 + ((kk * 4 + lg) ^ sw) * 8];
          sc[n] = __builtin_amdgcn_mfma_f32_16x16x32_bf16(qf[kk], kf, sc[n], 0, 0, 0);
        }

      if (kt == qt) {  // diagonal tile: causal mask
#pragma unroll
        for (int n = 0; n < 4; ++n)
#pragma unroll
          for (int r = 0; r < 4; ++r)
            if (n * 16 + lr > w * 16 + lg * 4 + r) sc[n][r] = -1e30f;
      }

      // online softmax (row = lg*4 + r; 16 lanes hold the cols)
#pragma unroll
      for (int r = 0; r < 4; ++r) {
        float pm = fmaxf(fmaxf(sc[0][r], sc[1][r]), fmaxf(sc[2][r], sc[3][r]));
#pragma unroll
        for (int off = 8; off > 0; off >>= 1) pm = fmaxf(pm, __shfl_xor(pm, off));
        float mn = fmaxf(mrow[r], pm);
        float corr = __expf(mrow[r] - mn);
        mrow[r] = mn;
        float ps = 0.f;
#pragma unroll
        for (int n = 0; n < 4; ++n) { sc[n][r] = __expf(sc[n][r] - mn); ps += sc[n][r]; }
#pragma unroll
        for (int off = 8; off > 0; off >>= 1) ps += __shfl_xor(ps, off);
        lsum[r] = lsum[r] * corr + ps;
#pragma unroll
        for (int dn = 0; dn < 8; ++dn) oacc[dn][r] *= corr;
      }

      // P -> LDS (swizzled)
#pragma unroll
      for (int n = 0; n < 4; ++n)
#pragma unroll
        for (int r = 0; r < 4; ++r) {
          int row = lg * 4 + r;
          Ps[w][row * 64 + (((n * 2 + (lr >> 3)) ^ (row & 7)) * 8) + (lr & 7)] = (__bf16)sc[n][r];
        }

      // O += P V
#pragma unroll
      for (int ks = 0; ks < 2; ++ks) {
        bf16x8 pf = *(const bf16x8*)&Ps[w][lr * 64 + ((ks * 4 + lg) ^ sw) * 8];
#pragma unroll
        for (int dn = 0; dn < 8; ++dn) {
          bf16x8 vf = *(const bf16x8*)&Vs[(dn * 16 + lr) * 64 + ((ks * 4 + lg) ^ sw) * 8];
          oacc[dn] = __builtin_amdgcn_mfma_f32_16x16x32_bf16(pf, vf, oacc[dn], 0, 0, 0);
        }
      }
      __syncthreads();
    }

    __bf16* Ob = attno + (size_t)(b * SEQ + qt * 64 + w * 16) * DIMSZ + h * 128;
#pragma unroll
    for (int dn = 0; dn < 8; ++dn)
#pragma unroll
      for (int r = 0; r < 4; ++r)
        Ob[(size_t)(lg * 4 + r) * DIMSZ + dn * 16 + lr] = (__bf16)(oacc[dn][r] / lsum[r]);
  }
}

// ---------------- host launcher --------------------------------------------
extern "C" void kernel_launch(void* const* d_in, const int* in_sizes, int n_in,
                              void* d_out, int out_size, void* d_ws, size_t ws_size,
                              hipStream_t stream) {
  const float* x    = (const float*)d_in[0];
  const float* wq   = (const float*)d_in[1];
  const float* wk   = (const float*)d_in[2];
  const float* wv   = (const float*)d_in[3];
  const float* wo   = (const float*)d_in[4];
  const float* cosT = (const float*)d_in[5];
  const float* sinT = (const float*)d_in[6];
  // d_in[7] (mask) implemented as causal; d_in[8] (start_pos) == 0.

  char* ws = (char*)d_ws;
  __bf16* xb    = (__bf16*)(ws);                    // 4096x4096        (32 MiB)
  __bf16* wqkvb = (__bf16*)(ws + 33554432);         // 6144x4096        (48 MiB)
  __bf16* qkvb  = (__bf16*)(ws + 83886080);         // 4096x6144        (48 MiB)
  __bf16* wob   = (__bf16*)(ws + 134217728);        // 4096x4096        (32 MiB)
  __bf16* vt    = (__bf16*)(ws + 167772160);        // 16x128x2048      ( 8 MiB)
  __bf16* attno = (__bf16*)(ws + 176160768);        // 4096x4096        (32 MiB)
  float* out = (float*)d_out;

  // fp32 -> bf16 conversions (wq/wk/wv concatenated into one 6144x4096 weight)
  k_cvt<<<8192, 256, 0, stream>>>(x, xb, 16777216L);
  k_cvt<<<8192, 256, 0, stream>>>(wq, wqkvb, 16777216L);
  k_cvt<<<2048, 256, 0, stream>>>(wk, wqkvb + 16777216, 4194304L);
  k_cvt<<<2048, 256, 0, stream>>>(wv, wqkvb + 20971520, 4194304L);
  k_cvt<<<8192, 256, 0, stream>>>(wo, wob, 16777216L);

  // QKV projection: M=4096, N=6144 -> grid (24, 16), bn fastest
  k_gemm256<__bf16><<<dim3(24, 16), 512, 0, stream>>>(xb, wqkvb, qkvb, 4096, QKVN, 4096);
  // RoPE + RMSNorm on Q,K (in place), attention scale folded into Q
  k_rope_norm<<<40960, 256, 0, stream>>>(qkvb, cosT, sinT);
  // V -> V^T for contiguous PV operand reads
  k_transpose_v<<<dim3(32, 16), 256, 0, stream>>>(qkvb, vt);
  // causal GQA flash attention (paired q-tiles for balance)
  k_flash<<<dim3(16, 64), 256, 0, stream>>>(qkvb, vt, attno);
  // output projection: M=4096, N=4096 -> grid (16, 16)
  k_gemm256<float><<<dim3(16, 16), 512, 0, stream>>>(attno, wob, out, 4096, DIMSZ, 4096);
}

// Round 9
// 613.691 us; speedup vs baseline: 1.1743x; 1.0282x over previous
//
#include <hip/hip_runtime.h>
#include <hip/hip_bf16.h>
#include <stdint.h>

#define SEQ 2048
#define DIMSZ 4096
#define QKVN 6144   // 4096 Q + 1024 K + 1024 V

typedef __attribute__((ext_vector_type(8))) __bf16 bf16x8;
typedef __attribute__((ext_vector_type(4))) float f32x4;

// async global->LDS, 16B per lane; dest = wave-uniform base + lane*16
static __device__ __forceinline__ void gld_lds16(const void* g, void* l) {
  __builtin_amdgcn_global_load_lds(
      (__attribute__((address_space(1))) void*)(g),
      (__attribute__((address_space(3))) void*)(l), 16, 0, 0);
}

static __device__ __forceinline__ void blockbar() {
  asm volatile("" ::: "memory");
  __builtin_amdgcn_s_barrier();
  asm volatile("" ::: "memory");
}

// ---------------- fp32 -> bf16 conversion (vectorized) ----------------
__global__ __launch_bounds__(256) void k_cvt(const float* __restrict__ in,
                                             __bf16* __restrict__ out, long n) {
  long i = (long)blockIdx.x * 256 + threadIdx.x;
  long stride = (long)gridDim.x * 256;
  for (long e = i * 8; e < n; e += stride * 8) {
    float4 v0 = *(const float4*)(in + e);
    float4 v1 = *(const float4*)(in + e + 4);
    bf16x8 o;
    o[0] = (__bf16)v0.x; o[1] = (__bf16)v0.y; o[2] = (__bf16)v0.z; o[3] = (__bf16)v0.w;
    o[4] = (__bf16)v1.x; o[5] = (__bf16)v1.y; o[6] = (__bf16)v1.z; o[7] = (__bf16)v1.w;
    *(bf16x8*)(out + e) = o;
  }
}

// ---------------- bf16 GEMM, C = A * B^T  (round-8 version, unchanged) -----
// 256x256 tile, BK=64, 512 thr (8 waves, 2M x 4N), 128 KiB LDS, 4 sub-phases
// per K-tile, counted vmcnt(4) at the tile boundary only. Intrinsic rate
// ~1030 TF (tail-corrected, round-8 counters); GEMM1's 384-block grid at
// 1 block/CU pays a 1.5-round packing tail (structural: 128-reg acc + 128 KiB
// LDS both cap at 8 waves/CU; no geometry fixes 384%256 — verified r8 PM).
template <typename OutT>
__global__ __launch_bounds__(512) void k_gemm256(const __bf16* __restrict__ A,
                                                 const __bf16* __restrict__ B,
                                                 OutT* __restrict__ C,
                                                 int M, int N, int K) {
  __shared__ __align__(16) __bf16 As[2][2][128 * 64];  // 64 KiB
  __shared__ __align__(16) __bf16 Bs[2][2][128 * 64];  // 64 KiB
  const int t = threadIdx.x;
  const int l = t & 63;
  const int w = t >> 6;        // 0..7
  const int wm = w >> 2;       // 0..1 : C rows [wm*128, +128) == A half wm
  const int wn = w & 3;        // 0..3 : C cols [wn*64, +64)  == B half wn>>1
  const int lr = l & 15, lg = l >> 4;
  const int sw = lr & 7;       // read-side chunk XOR (row&7 == lr&7, rows %16)
  const int bm = blockIdx.y, bn = blockIdx.x;

  const int srow = t >> 3;
  const int scol = ((t & 7) ^ (srow & 7)) << 3;
  const __bf16* pa0 = A + (size_t)(bm * 256 +   0 + srow) * K + scol;
  const __bf16* pa1 = A + (size_t)(bm * 256 +  64 + srow) * K + scol;
  const __bf16* pa2 = A + (size_t)(bm * 256 + 128 + srow) * K + scol;
  const __bf16* pa3 = A + (size_t)(bm * 256 + 192 + srow) * K + scol;
  const __bf16* pb0 = B + (size_t)(bn * 256 +   0 + srow) * K + scol;
  const __bf16* pb1 = B + (size_t)(bn * 256 +  64 + srow) * K + scol;
  const __bf16* pb2 = B + (size_t)(bn * 256 + 128 + srow) * K + scol;
  const __bf16* pb3 = B + (size_t)(bn * 256 + 192 + srow) * K + scol;
  const int ldst = t * 8;

#define STAGE_A(buf, kc)                              \
  do {                                                \
    gld_lds16(pa0 + (kc), &As[buf][0][ldst]);         \
    gld_lds16(pa1 + (kc), &As[buf][0][4096 + ldst]);  \
    gld_lds16(pa2 + (kc), &As[buf][1][ldst]);         \
    gld_lds16(pa3 + (kc), &As[buf][1][4096 + ldst]);  \
  } while (0)
#define STAGE_B0(buf, kc)                             \
  do {                                                \
    gld_lds16(pb0 + (kc), &Bs[buf][0][ldst]);         \
    gld_lds16(pb1 + (kc), &Bs[buf][0][4096 + ldst]);  \
  } while (0)
#define STAGE_B1(buf, kc)                             \
  do {                                                \
    gld_lds16(pb2 + (kc), &Bs[buf][1][ldst]);         \
    gld_lds16(pb3 + (kc), &Bs[buf][1][4096 + ldst]);  \
  } while (0)

  const int c0 = ((lg ^ sw) * 8);          // kk=0
  const int c1 = (((lg ^ sw) ^ 4) * 8);    // kk=1
  const int aRow = lr;
  const int bRow = (wn & 1) * 64 + lr;

  f32x4 acc[8][4] = {};
  const int nt = K >> 6;

  STAGE_A(0, 0);
  STAGE_B0(0, 0);
  STAGE_B1(0, 0);
  STAGE_A(1, (nt > 1 ? 64 : 0));
  asm volatile("s_waitcnt vmcnt(4)" ::: "memory");
  blockbar();

  for (int T = 0; T < nt; ++T) {
    const int cur = T & 1;
    const int kB = (T + 1 < nt ? T + 1 : nt - 1) << 6;
    const int kA = (T + 2 < nt ? T + 2 : nt - 1) << 6;
    bf16x8 a[4][2], b0[2][2], b1[2][2];

    // ---------- phase 0: a03 x b01 ----------
#pragma unroll
    for (int mi = 0; mi < 4; ++mi) {
      a[mi][0] = *(const bf16x8*)&As[cur][wm][(mi * 16 + aRow) * 64 + c0];
      a[mi][1] = *(const bf16x8*)&As[cur][wm][(mi * 16 + aRow) * 64 + c1];
    }
#pragma unroll
    for (int ni = 0; ni < 2; ++ni) {
      b0[ni][0] = *(const bf16x8*)&Bs[cur][wn >> 1][(ni * 16 + bRow) * 64 + c0];
      b0[ni][1] = *(const bf16x8*)&Bs[cur][wn >> 1][(ni * 16 + bRow) * 64 + c1];
    }
    STAGE_B0((T + 1) & 1, kB);
    blockbar();
    __builtin_amdgcn_s_setprio(1);
#pragma unroll
    for (int mi = 0; mi < 4; ++mi)
#pragma unroll
      for (int ni = 0; ni < 2; ++ni)
#pragma unroll
        for (int kk = 0; kk < 2; ++kk)
          acc[mi][ni] = __builtin_amdgcn_mfma_f32_16x16x32_bf16(a[mi][kk], b0[ni][kk], acc[mi][ni], 0, 0, 0);
    __builtin_amdgcn_s_setprio(0);
    blockbar();

    // ---------- phase 1: a03 x b23 ----------
#pragma unroll
    for (int ni = 0; ni < 2; ++ni) {
      b1[ni][0] = *(const bf16x8*)&Bs[cur][wn >> 1][((ni + 2) * 16 + bRow) * 64 + c0];
      b1[ni][1] = *(const bf16x8*)&Bs[cur][wn >> 1][((ni + 2) * 16 + bRow) * 64 + c1];
    }
    STAGE_B1((T + 1) & 1, kB);
    blockbar();
    __builtin_amdgcn_s_setprio(1);
#pragma unroll
    for (int mi = 0; mi < 4; ++mi)
#pragma unroll
      for (int ni = 0; ni < 2; ++ni)
#pragma unroll
        for (int kk = 0; kk < 2; ++kk)
          acc[mi][ni + 2] = __builtin_amdgcn_mfma_f32_16x16x32_bf16(a[mi][kk], b1[ni][kk], acc[mi][ni + 2], 0, 0, 0);
    __builtin_amdgcn_s_setprio(0);
    blockbar();

    // ---------- phase 2: a47 x b23 ----------
#pragma unroll
    for (int mi = 0; mi < 4; ++mi) {
      a[mi][0] = *(const bf16x8*)&As[cur][wm][((mi + 4) * 16 + aRow) * 64 + c0];
      a[mi][1] = *(const bf16x8*)&As[cur][wm][((mi + 4) * 16 + aRow) * 64 + c1];
    }
    blockbar();
    __builtin_amdgcn_s_setprio(1);
#pragma unroll
    for (int mi = 0; mi < 4; ++mi)
#pragma unroll
      for (int ni = 0; ni < 2; ++ni)
#pragma unroll
        for (int kk = 0; kk < 2; ++kk)
          acc[mi + 4][ni + 2] = __builtin_amdgcn_mfma_f32_16x16x32_bf16(a[mi][kk], b1[ni][kk], acc[mi + 4][ni + 2], 0, 0, 0);
    __builtin_amdgcn_s_setprio(0);
    blockbar();

    // ---------- phase 3: a47 x b01; stage A(T+2) ----------
    STAGE_A(cur, kA);
    blockbar();
    __builtin_amdgcn_s_setprio(1);
#pragma unroll
    for (int mi = 0; mi < 4; ++mi)
#pragma unroll
      for (int ni = 0; ni < 2; ++ni)
#pragma unroll
        for (int kk = 0; kk < 2; ++kk)
          acc[mi + 4][ni] = __builtin_amdgcn_mfma_f32_16x16x32_bf16(a[mi][kk], b0[ni][kk], acc[mi + 4][ni], 0, 0, 0);
    __builtin_amdgcn_s_setprio(0);
    asm volatile("s_waitcnt vmcnt(4)" ::: "memory");
    blockbar();
  }
#undef STAGE_A
#undef STAGE_B0
#undef STAGE_B1

  const int row0 = bm * 256 + wm * 128;
  const int col0 = bn * 256 + wn * 64;
#pragma unroll
  for (int mi = 0; mi < 8; ++mi)
#pragma unroll
    for (int ni = 0; ni < 4; ++ni)
#pragma unroll
      for (int r = 0; r < 4; ++r)
        C[(size_t)(row0 + mi * 16 + lg * 4 + r) * N + (col0 + ni * 16 + lr)] =
            (OutT)acc[mi][ni][r];
}

// ---------------- fused RoPE + RMSNorm (in-place on Q and K regions) -------
__global__ __launch_bounds__(256) void k_rope_norm(__bf16* __restrict__ qkv,
                                                   const float* __restrict__ cosT,
                                                   const float* __restrict__ sinT) {
  const int task = blockIdx.x * 4 + (threadIdx.x >> 6);
  const int l = threadIdx.x & 63;
  const int m = task / 40;          // row in [0, 4096)
  const int h = task - m * 40;      // 0..31 = Q heads, 32..39 = K heads
  const int s = m & (SEQ - 1);
  const bool isQ = h < 32;
  const int col = isQ ? h * 128 : 4096 + (h - 32) * 128;
  __bf16* p = qkv + (size_t)m * QKVN + col + l * 2;
  float e = (float)p[0], o = (float)p[1];
  float c = cosT[s * 64 + l], sn = sinT[s * 64 + l];
  float e2 = e * c - o * sn;
  float o2 = e * sn + o * c;
  float ss = e2 * e2 + o2 * o2;
#pragma unroll
  for (int off = 32; off > 0; off >>= 1) ss += __shfl_xor(ss, off);
  float r = rsqrtf(ss * (1.0f / 128.0f) + 1e-5f);
  if (isQ) r *= 0.08838834764831845f;  // fold 1/sqrt(HEAD_DIM) into Q
  p[0] = (__bf16)(e2 * r);
  p[1] = (__bf16)(o2 * r);
}

// ---------------- V transpose: qkv V region (b,s,g,d) -> vt (b,g,d,s) ------
__global__ __launch_bounds__(256) void k_transpose_v(const __bf16* __restrict__ qkv,
                                                     __bf16* __restrict__ vt) {
  __shared__ __bf16 tile[64][136];  // padded row, no bank conflicts
  const int t = threadIdx.x;
  const int st = blockIdx.x, bg = blockIdx.y;
  const int b = bg >> 3, g = bg & 7;
  const int s0 = st * 64;
#pragma unroll
  for (int p = 0; p < 4; ++p) {
    int row = p * 16 + (t >> 4);
    int co = (t & 15) * 8;
    *(bf16x8*)&tile[row][co] =
        *(const bf16x8*)&qkv[(size_t)(b * SEQ + s0 + row) * QKVN + 5120 + g * 128 + co];
  }
  __syncthreads();
#pragma unroll
  for (int p = 0; p < 4; ++p) {
    int d = p * 32 + (t >> 3);
    int so = (t & 7) * 8;
    bf16x8 v;
#pragma unroll
    for (int j = 0; j < 8; ++j) v[j] = tile[so + j][d];
    *(bf16x8*)&vt[((size_t)bg * 128 + d) * SEQ + s0 + so] = v;
  }
}

// ---------------- causal flash attention (GQA) ------------------------------
// ROUND-9 CHANGES (flash only): T13 defer-max (THR=8) wave-uniform fast path
// skipping {16-lane shfl-max, mrow update, corr exp, oacc rescale}; T5
// setprio around QK/PV MFMA clusters (independent-block regime, m191);
// hoisted staging base pointers; rcp-mult epilogue.
__global__ __launch_bounds__(256) void k_flash(const __bf16* __restrict__ qkv,
                                               const __bf16* __restrict__ vt,
                                               __bf16* __restrict__ attno) {
  __shared__ __bf16 Ks[64 * 128];   // [kv][d], swizzled
  __shared__ __bf16 Vs[128 * 64];   // [d][kv], swizzled
  __shared__ __bf16 Ps[4][16 * 64]; // per-wave [q][kv], swizzled
  const int t = threadIdx.x, w = t >> 6, l = t & 63;
  const int lr = l & 15, lg = l >> 4;
  const int bh = blockIdx.y;        // b*32 + h
  const int b = bh >> 5, h = bh & 31, g = h >> 2;
  const int qt0 = blockIdx.x, qt1 = 31 - (int)blockIdx.x;

  // hoisted staging bases (swizzle term constant across tiles: i*16 ≡ 0 mod 8)
  const __bf16* kp = qkv + 4096 + (size_t)(b * SEQ + (t >> 4)) * QKVN + g * 128 +
                     (((t & 15) ^ ((t >> 4) & 7)) * 8);
  const __bf16* vp = vt + (size_t)(b * 8 + g) * 128 * SEQ + (size_t)(t >> 3) * SEQ +
                     (((t & 7) ^ ((t >> 3) & 7)) * 8);
  const int wbase = (t & ~63) * 8;
  const int sw = lr & 7;            // read-side XOR (row&7 == lr&7 everywhere)

  for (int pass = 0; pass < 2; ++pass) {
    const int qt = (pass == 0) ? qt0 : qt1;

    const __bf16* Qb = qkv + (size_t)(b * SEQ + qt * 64 + w * 16 + lr) * QKVN + h * 128;
    bf16x8 qf[4];
#pragma unroll
    for (int kk = 0; kk < 4; ++kk) qf[kk] = *(const bf16x8*)&Qb[kk * 32 + lg * 8];

    f32x4 oacc[8] = {};
    float mrow[4], lsum[4];
#pragma unroll
    for (int r = 0; r < 4; ++r) { mrow[r] = -1e30f; lsum[r] = 0.f; }

    for (int kt = 0; kt <= qt; ++kt) {
      const size_t kv0 = (size_t)kt * 64;
#pragma unroll
      for (int i = 0; i < 4; ++i)
        gld_lds16(kp + (kv0 + i * 16) * QKVN, &Ks[i * 2048 + wbase]);
#pragma unroll
      for (int i = 0; i < 4; ++i)
        gld_lds16(vp + (size_t)i * 32 * SEQ + kv0, &Vs[i * 2048 + wbase]);
      __syncthreads();

      // S = Q K^T
      f32x4 sc[4] = {};
      __builtin_amdgcn_s_setprio(1);
#pragma unroll
      for (int kk = 0; kk < 4; ++kk)
#pragma unroll
        for (int n = 0; n < 4; ++n) {
          bf16x8 kf = *(const bf16x8*)&Ks[(n * 16 + lr) * 128 + ((kk * 4 + lg) ^ sw) * 8];
          sc[n] = __builtin_amdgcn_mfma_f32_16x16x32_bf16(qf[kk], kf, sc[n], 0, 0, 0);
        }
      __builtin_amdgcn_s_setprio(0);

      if (kt == qt) {  // diagonal tile: causal mask
#pragma unroll
        for (int n = 0; n < 4; ++n)
#pragma unroll
          for (int r = 0; r < 4; ++r)
            if (n * 16 + lr > w * 16 + lg * 4 + r) sc[n][r] = -1e30f;
      }

      // online softmax with defer-max (T13, THR=8). Rows = lg*4+r; the
      // __all covers all 64 lanes -> all 16 rows and 64 cols: sound.
      float pml[4];
      float need = -1e30f;
#pragma unroll
      for (int r = 0; r < 4; ++r) {
        pml[r] = fmaxf(fmaxf(sc[0][r], sc[1][r]), fmaxf(sc[2][r], sc[3][r]));
        need = fmaxf(need, pml[r] - mrow[r]);
      }
      if (__all(need <= 8.0f)) {
        // fast path: keep old max (corr == 1): no shfl-max, no rescale.
        // P bounded by e^8 ~ 2981 (bf16-safe); lsum fp32 accumulates fine.
#pragma unroll
        for (int r = 0; r < 4; ++r) {
          float ps = 0.f;
#pragma unroll
          for (int n = 0; n < 4; ++n) { sc[n][r] = __expf(sc[n][r] - mrow[r]); ps += sc[n][r]; }
#pragma unroll
          for (int off = 8; off > 0; off >>= 1) ps += __shfl_xor(ps, off);
          lsum[r] += ps;
        }
      } else {
#pragma unroll
        for (int r = 0; r < 4; ++r) {
          float pm = pml[r];
#pragma unroll
          for (int off = 8; off > 0; off >>= 1) pm = fmaxf(pm, __shfl_xor(pm, off));
          float mn = fmaxf(mrow[r], pm);
          float corr = __expf(mrow[r] - mn);
          mrow[r] = mn;
          float ps = 0.f;
#pragma unroll
          for (int n = 0; n < 4; ++n) { sc[n][r] = __expf(sc[n][r] - mn); ps += sc[n][r]; }
#pragma unroll
          for (int off = 8; off > 0; off >>= 1) ps += __shfl_xor(ps, off);
          lsum[r] = lsum[r] * corr + ps;
#pragma unroll
          for (int dn = 0; dn < 8; ++dn) oacc[dn][r] *= corr;
        }
      }

      // P -> LDS (swizzled)
#pragma unroll
      for (int n = 0; n < 4; ++n)
#pragma unroll
        for (int r = 0; r < 4; ++r) {
          int row = lg * 4 + r;
          Ps[w][row * 64 + (((n * 2 + (lr >> 3)) ^ (row & 7)) * 8) + (lr & 7)] = (__bf16)sc[n][r];
        }

      // O += P V
      __builtin_amdgcn_s_setprio(1);
#pragma unroll
      for (int ks = 0; ks < 2; ++ks) {
        bf16x8 pf = *(const bf16x8*)&Ps[w][lr * 64 + ((ks * 4 + lg) ^ sw) * 8];
#pragma unroll
        for (int dn = 0; dn < 8; ++dn) {
          bf16x8 vf = *(const bf16x8*)&Vs[(dn * 16 + lr) * 64 + ((ks * 4 + lg) ^ sw) * 8];
          oacc[dn] = __builtin_amdgcn_mfma_f32_16x16x32_bf16(pf, vf, oacc[dn], 0, 0, 0);
        }
      }
      __builtin_amdgcn_s_setprio(0);
      __syncthreads();
    }

    float inv[4];
#pragma unroll
    for (int r = 0; r < 4; ++r) inv[r] = __builtin_amdgcn_rcpf(lsum[r]);
    __bf16* Ob = attno + (size_t)(b * SEQ + qt * 64 + w * 16) * DIMSZ + h * 128;
#pragma unroll
    for (int dn = 0; dn < 8; ++dn)
#pragma unroll
      for (int r = 0; r < 4; ++r)
        Ob[(size_t)(lg * 4 + r) * DIMSZ + dn * 16 + lr] = (__bf16)(oacc[dn][r] * inv[r]);
  }
}

// ---------------- host launcher --------------------------------------------
extern "C" void kernel_launch(void* const* d_in, const int* in_sizes, int n_in,
                              void* d_out, int out_size, void* d_ws, size_t ws_size,
                              hipStream_t stream) {
  const float* x    = (const float*)d_in[0];
  const float* wq   = (const float*)d_in[1];
  const float* wk   = (const float*)d_in[2];
  const float* wv   = (const float*)d_in[3];
  const float* wo   = (const float*)d_in[4];
  const float* cosT = (const float*)d_in[5];
  const float* sinT = (const float*)d_in[6];
  // d_in[7] (mask) implemented as causal; d_in[8] (start_pos) == 0.

  char* ws = (char*)d_ws;
  __bf16* xb    = (__bf16*)(ws);                    // 4096x4096        (32 MiB)
  __bf16* wqkvb = (__bf16*)(ws + 33554432);         // 6144x4096        (48 MiB)
  __bf16* qkvb  = (__bf16*)(ws + 83886080);         // 4096x6144        (48 MiB)
  __bf16* wob   = (__bf16*)(ws + 134217728);        // 4096x4096        (32 MiB)
  __bf16* vt    = (__bf16*)(ws + 167772160);        // 16x128x2048      ( 8 MiB)
  __bf16* attno = (__bf16*)(ws + 176160768);        // 4096x4096        (32 MiB)
  float* out = (float*)d_out;

  // fp32 -> bf16 conversions (wq/wk/wv concatenated into one 6144x4096 weight)
  k_cvt<<<8192, 256, 0, stream>>>(x, xb, 16777216L);
  k_cvt<<<8192, 256, 0, stream>>>(wq, wqkvb, 16777216L);
  k_cvt<<<2048, 256, 0, stream>>>(wk, wqkvb + 16777216, 4194304L);
  k_cvt<<<2048, 256, 0, stream>>>(wv, wqkvb + 20971520, 4194304L);
  k_cvt<<<8192, 256, 0, stream>>>(wo, wob, 16777216L);

  // QKV projection: M=4096, N=6144 -> grid (24, 16), bn fastest
  k_gemm256<__bf16><<<dim3(24, 16), 512, 0, stream>>>(xb, wqkvb, qkvb, 4096, QKVN, 4096);
  // RoPE + RMSNorm on Q,K (in place), attention scale folded into Q
  k_rope_norm<<<40960, 256, 0, stream>>>(qkvb, cosT, sinT);
  // V -> V^T for contiguous PV operand reads
  k_transpose_v<<<dim3(32, 16), 256, 0, stream>>>(qkvb, vt);
  // causal GQA flash attention (paired q-tiles for balance)
  k_flash<<<dim3(16, 64), 256, 0, stream>>>(qkvb, vt, attno);
  // output projection: M=4096, N=4096 -> grid (16, 16)
  k_gemm256<float><<<dim3(16, 16), 512, 0, stream>>>(attno, wob, out, 4096, DIMSZ, 4096);
}

// Round 10
// 597.873 us; speedup vs baseline: 1.2054x; 1.0265x over previous
//
#include <hip/hip_runtime.h>
#include <hip/hip_bf16.h>
#include <stdint.h>

#define SEQ 2048
#define DIMSZ 4096
#define QKVN 6144   // 4096 Q + 1024 K + 1024 V

typedef __attribute__((ext_vector_type(8))) __bf16 bf16x8;
typedef __attribute__((ext_vector_type(4))) float f32x4;

// async global->LDS, 16B per lane; dest = wave-uniform base + lane*16
static __device__ __forceinline__ void gld_lds16(const void* g, void* l) {
  __builtin_amdgcn_global_load_lds(
      (__attribute__((address_space(1))) void*)(g),
      (__attribute__((address_space(3))) void*)(l), 16, 0, 0);
}

// ---------------- merged fp32 -> bf16 conversion (one launch, 5 segments) --
__global__ __launch_bounds__(256) void k_cvt5(const float* __restrict__ x,
                                              const float* __restrict__ wq,
                                              const float* __restrict__ wk,
                                              const float* __restrict__ wv,
                                              const float* __restrict__ wo,
                                              __bf16* __restrict__ xb,
                                              __bf16* __restrict__ wqkvb,
                                              __bf16* __restrict__ wob) {
  // in units of 8-elem vectors: x 2097152 | wq 2097152 | wk 524288 | wv 524288 | wo 2097152
  long vid = (long)blockIdx.x * 256 + threadIdx.x;
  const long stride = (long)gridDim.x * 256;
  for (; vid < 7340032L; vid += stride) {
    const float* src; __bf16* dst; long off;
    if (vid < 2097152L)      { src = x;  dst = xb;                off = vid; }
    else if (vid < 4194304L) { src = wq; dst = wqkvb;             off = vid - 2097152L; }
    else if (vid < 4718592L) { src = wk; dst = wqkvb + 16777216L; off = vid - 4194304L; }
    else if (vid < 5242880L) { src = wv; dst = wqkvb + 20971520L; off = vid - 4718592L; }
    else                     { src = wo; dst = wob;               off = vid - 5242880L; }
    const long e = off * 8;
    float4 v0 = *(const float4*)(src + e);
    float4 v1 = *(const float4*)(src + e + 4);
    bf16x8 o;
    o[0] = (__bf16)v0.x; o[1] = (__bf16)v0.y; o[2] = (__bf16)v0.z; o[3] = (__bf16)v0.w;
    o[4] = (__bf16)v1.x; o[5] = (__bf16)v1.y; o[6] = (__bf16)v1.z; o[7] = (__bf16)v1.w;
    *(bf16x8*)(dst + e) = o;
  }
}

// ---------------- bf16 GEMM, C = A * B^T  (A: MxK, B: NxK, both K-contig) --
// Faithful m201 8-phase schedule: 256x256, BK=64, 512 thr (8 waves 2Mx4N),
// LDS [2buf][2half][128x64] per operand (128 KiB). One iter = 2 K-tiles
// (T0=2i->buf0, T1=2i+1->buf1), 8 phases; each phase:
//   { ds_read this phase's frags; stage EXACTLY 1 half-tile (2 gld_lds);
//     s_barrier; s_waitcnt lgkmcnt(0) [no sched_barrier - m141];
//     setprio(1); 16 MFMA; setprio(0); [ph3/ph7: s_waitcnt vmcnt(4)];
//     s_barrier }
// Stagger map (stage -> first read, all leads 4-6 phases; each slot staged
// >=1 phase after its buffer's last read — derived & checked r9 PM):
//   ph0:A1(T1) ph1:B1(T1) ph2:B0(T0+2) ph3:A0(T0+2)
//   ph4:A1(T0+2) ph5:B1(T0+2) ph6:B0(T1+2) ph7:A0(T1+2)
// vmcnt(4) at ph3 retires {B0,A0 (prev ph6,7), A1,B1 (ph0,1)} = tile T1's
// 4 halves; at ph7 retires tile T0+2's 4 halves. Counted, never 0.
// T2 swizzle: 16B chunk ^= row&7 via pre-swizzled global source (0 conflicts
// measured r5-r9). Every wave runs vmcnt before each barrier -> all waves'
// DMA landed once the barrier is crossed (r7/r8 pattern, verified passing).
template <typename OutT>
__global__ __launch_bounds__(512) void k_gemm8p(const __bf16* __restrict__ A,
                                                const __bf16* __restrict__ B,
                                                OutT* __restrict__ C,
                                                int M, int N, int K) {
  __shared__ __align__(16) __bf16 As[2][2][128 * 64];  // 64 KiB
  __shared__ __align__(16) __bf16 Bs[2][2][128 * 64];  // 64 KiB
  const int t = threadIdx.x;
  const int l = t & 63;
  const int w = t >> 6;        // 0..7
  const int wm = w >> 2;       // 0..1 : A half
  const int wn = w & 3;        // 0..3 : B half = wn>>1, 64-row slice = wn&1
  const int lr = l & 15, lg = l >> 4;
  const int sw = lr & 7;       // read-side chunk XOR
  const int bm = blockIdx.y, bn = blockIdx.x;

  const int srow = t >> 3;
  const int scol = ((t & 7) ^ (srow & 7)) << 3;
  const __bf16* pa0 = A + (size_t)(bm * 256 +   0 + srow) * K + scol;
  const __bf16* pa1 = A + (size_t)(bm * 256 +  64 + srow) * K + scol;
  const __bf16* pa2 = A + (size_t)(bm * 256 + 128 + srow) * K + scol;
  const __bf16* pa3 = A + (size_t)(bm * 256 + 192 + srow) * K + scol;
  const __bf16* pb0 = B + (size_t)(bn * 256 +   0 + srow) * K + scol;
  const __bf16* pb1 = B + (size_t)(bn * 256 +  64 + srow) * K + scol;
  const __bf16* pb2 = B + (size_t)(bn * 256 + 128 + srow) * K + scol;
  const __bf16* pb3 = B + (size_t)(bn * 256 + 192 + srow) * K + scol;
  const int ldst = t * 8;

#define SA0(buf, kc) { gld_lds16(pa0 + (kc), &As[buf][0][ldst]); gld_lds16(pa1 + (kc), &As[buf][0][4096 + ldst]); }
#define SA1(buf, kc) { gld_lds16(pa2 + (kc), &As[buf][1][ldst]); gld_lds16(pa3 + (kc), &As[buf][1][4096 + ldst]); }
#define SB0(buf, kc) { gld_lds16(pb0 + (kc), &Bs[buf][0][ldst]); gld_lds16(pb1 + (kc), &Bs[buf][0][4096 + ldst]); }
#define SB1(buf, kc) { gld_lds16(pb2 + (kc), &Bs[buf][1][ldst]); gld_lds16(pb3 + (kc), &Bs[buf][1][4096 + ldst]); }

  const int c0 = ((lg ^ sw) * 8);
  const int c1 = (((lg ^ sw) ^ 4) * 8);
  const int aRow = lr;
  const int bRow = (wn & 1) * 64 + lr;

#define RDA(mi0, cur)                                                          \
  _Pragma("unroll") for (int mi = 0; mi < 4; ++mi) {                           \
    a[mi][0] = *(const bf16x8*)&As[cur][wm][(((mi0) + mi) * 16 + aRow) * 64 + c0]; \
    a[mi][1] = *(const bf16x8*)&As[cur][wm][(((mi0) + mi) * 16 + aRow) * 64 + c1]; \
  }
#define RDB(bv, ni0, cur)                                                      \
  _Pragma("unroll") for (int ni = 0; ni < 2; ++ni) {                           \
    bv[ni][0] = *(const bf16x8*)&Bs[cur][wn >> 1][(((ni0) + ni) * 16 + bRow) * 64 + c0]; \
    bv[ni][1] = *(const bf16x8*)&Bs[cur][wn >> 1][(((ni0) + ni) * 16 + bRow) * 64 + c1]; \
  }
#define PHTOP()                                        \
  asm volatile("" ::: "memory");                       \
  __builtin_amdgcn_s_barrier();                        \
  asm volatile("s_waitcnt lgkmcnt(0)" ::: "memory");   \
  __builtin_amdgcn_s_setprio(1)
#define PHEND()                                        \
  __builtin_amdgcn_s_setprio(0);                       \
  asm volatile("" ::: "memory");                       \
  __builtin_amdgcn_s_barrier()
#define PHENDW()                                       \
  __builtin_amdgcn_s_setprio(0);                       \
  asm volatile("s_waitcnt vmcnt(4)" ::: "memory");     \
  __builtin_amdgcn_s_barrier()
#define MMA16(am0, bv, ni0)                                                    \
  _Pragma("unroll") for (int mi = 0; mi < 4; ++mi)                             \
  _Pragma("unroll") for (int ni = 0; ni < 2; ++ni)                             \
  _Pragma("unroll") for (int kk = 0; kk < 2; ++kk)                             \
    acc[(am0) + mi][(ni0) + ni] = __builtin_amdgcn_mfma_f32_16x16x32_bf16(     \
        a[mi][kk], bv[ni][kk], acc[(am0) + mi][(ni0) + ni], 0, 0, 0);

  f32x4 acc[8][4] = {};
  const int nt = K >> 6;        // K-tiles (64 for K=4096), even
  const int niter = nt >> 1;

  // prologue: tile0 all 4 halves, then B0(1),A0(1) (steady-state ph6,7 slots)
  SB0(0, 0); SA0(0, 0); SA1(0, 0); SB1(0, 0);
  SB0(1, 64); SA0(1, 64);
  asm volatile("s_waitcnt vmcnt(4)" ::: "memory");   // tile 0 landed
  asm volatile("" ::: "memory");
  __builtin_amdgcn_s_barrier();
  asm volatile("" ::: "memory");

  for (int i = 0; i < niter; ++i) {
    const int kT1 = (2 * i + 1) << 6;
    const int k2  = (2 * i + 2 < nt ? 2 * i + 2 : nt - 1) << 6;
    const int k3  = (2 * i + 3 < nt ? 2 * i + 3 : nt - 1) << 6;
    bf16x8 a[4][2], b0[2][2], b1[2][2];

    // ---- ph0: T0 a03 x b01 ----
    RDA(0, 0); RDB(b0, 0, 0);
    SA1(1, kT1);
    PHTOP(); MMA16(0, b0, 0); PHEND();
    // ---- ph1: T0 a03 x b23 ----
    RDB(b1, 2, 0);
    SB1(1, kT1);
    PHTOP(); MMA16(0, b1, 2); PHEND();
    // ---- ph2: T0 a47 x b23 ----
    RDA(4, 0);
    SB0(0, k2);
    PHTOP(); MMA16(4, b1, 2); PHEND();
    // ---- ph3: T0 a47 x b01 (b01 held); vmcnt(4) retires T1's halves ----
    SA0(0, k2);
    PHTOP(); MMA16(4, b0, 0); PHENDW();

    // ---- ph4: T1 a03 x b01 ----
    RDA(0, 1); RDB(b0, 0, 1);
    SA1(0, k2);
    PHTOP(); MMA16(0, b0, 0); PHEND();
    // ---- ph5: T1 a03 x b23 ----
    RDB(b1, 2, 1);
    SB1(0, k2);
    PHTOP(); MMA16(0, b1, 2); PHEND();
    // ---- ph6: T1 a47 x b23 ----
    RDA(4, 1);
    SB0(1, k3);
    PHTOP(); MMA16(4, b1, 2); PHEND();
    // ---- ph7: T1 a47 x b01; vmcnt(4) retires T0+2's halves ----
    SA0(1, k3);
    PHTOP(); MMA16(4, b0, 0); PHENDW();
  }
#undef SA0
#undef SA1
#undef SB0
#undef SB1
#undef RDA
#undef RDB
#undef PHTOP
#undef PHEND
#undef PHENDW
#undef MMA16

  const int row0 = bm * 256 + wm * 128;
  const int col0 = bn * 256 + wn * 64;
#pragma unroll
  for (int mi = 0; mi < 8; ++mi)
#pragma unroll
    for (int ni = 0; ni < 4; ++ni)
#pragma unroll
      for (int r = 0; r < 4; ++r)
        C[(size_t)(row0 + mi * 16 + lg * 4 + r) * N + (col0 + ni * 16 + lr)] =
            (OutT)acc[mi][ni][r];
}

// ---------------- fused RoPE + RMSNorm (in-place on Q and K regions) -------
__global__ __launch_bounds__(256) void k_rope_norm(__bf16* __restrict__ qkv,
                                                   const float* __restrict__ cosT,
                                                   const float* __restrict__ sinT) {
  const int task = blockIdx.x * 4 + (threadIdx.x >> 6);
  const int l = threadIdx.x & 63;
  const int m = task / 40;          // row in [0, 4096)
  const int h = task - m * 40;      // 0..31 = Q heads, 32..39 = K heads
  const int s = m & (SEQ - 1);
  const bool isQ = h < 32;
  const int col = isQ ? h * 128 : 4096 + (h - 32) * 128;
  __bf16* p = qkv + (size_t)m * QKVN + col + l * 2;
  float e = (float)p[0], o = (float)p[1];
  float c = cosT[s * 64 + l], sn = sinT[s * 64 + l];
  float e2 = e * c - o * sn;
  float o2 = e * sn + o * c;
  float ss = e2 * e2 + o2 * o2;
#pragma unroll
  for (int off = 32; off > 0; off >>= 1) ss += __shfl_xor(ss, off);
  float r = rsqrtf(ss * (1.0f / 128.0f) + 1e-5f);
  if (isQ) r *= 0.08838834764831845f;  // fold 1/sqrt(HEAD_DIM) into Q
  p[0] = (__bf16)(e2 * r);
  p[1] = (__bf16)(o2 * r);
}

// ---------------- V transpose: qkv V region (b,s,g,d) -> vt (b,g,d,s) ------
__global__ __launch_bounds__(256) void k_transpose_v(const __bf16* __restrict__ qkv,
                                                     __bf16* __restrict__ vt) {
  __shared__ __bf16 tile[64][136];  // padded row, no bank conflicts
  const int t = threadIdx.x;
  const int st = blockIdx.x, bg = blockIdx.y;
  const int b = bg >> 3, g = bg & 7;
  const int s0 = st * 64;
#pragma unroll
  for (int p = 0; p < 4; ++p) {
    int row = p * 16 + (t >> 4);
    int co = (t & 15) * 8;
    *(bf16x8*)&tile[row][co] =
        *(const bf16x8*)&qkv[(size_t)(b * SEQ + s0 + row) * QKVN + 5120 + g * 128 + co];
  }
  __syncthreads();
#pragma unroll
  for (int p = 0; p < 4; ++p) {
    int d = p * 32 + (t >> 3);
    int so = (t & 7) * 8;
    bf16x8 v;
#pragma unroll
    for (int j = 0; j < 8; ++j) v[j] = tile[so + j][d];
    *(bf16x8*)&vt[((size_t)bg * 128 + d) * SEQ + s0 + so] = v;
  }
}

// ---------------- causal flash attention (GQA) — round-9 version -----------
__global__ __launch_bounds__(256) void k_flash(const __bf16* __restrict__ qkv,
                                               const __bf16* __restrict__ vt,
                                               __bf16* __restrict__ attno) {
  __shared__ __bf16 Ks[64 * 128];   // [kv][d], swizzled
  __shared__ __bf16 Vs[128 * 64];   // [d][kv], swizzled
  __shared__ __bf16 Ps[4][16 * 64]; // per-wave [q][kv], swizzled
  const int t = threadIdx.x, w = t >> 6, l = t & 63;
  const int lr = l & 15, lg = l >> 4;
  const int bh = blockIdx.y;        // b*32 + h
  const int b = bh >> 5, h = bh & 31, g = h >> 2;
  const int qt0 = blockIdx.x, qt1 = 31 - (int)blockIdx.x;

  const __bf16* kp = qkv + 4096 + (size_t)(b * SEQ + (t >> 4)) * QKVN + g * 128 +
                     (((t & 15) ^ ((t >> 4) & 7)) * 8);
  const __bf16* vp = vt + (size_t)(b * 8 + g) * 128 * SEQ + (size_t)(t >> 3) * SEQ +
                     (((t & 7) ^ ((t >> 3) & 7)) * 8);
  const int wbase = (t & ~63) * 8;
  const int sw = lr & 7;

  for (int pass = 0; pass < 2; ++pass) {
    const int qt = (pass == 0) ? qt0 : qt1;

    const __bf16* Qb = qkv + (size_t)(b * SEQ + qt * 64 + w * 16 + lr) * QKVN + h * 128;
    bf16x8 qf[4];
#pragma unroll
    for (int kk = 0; kk < 4; ++kk) qf[kk] = *(const bf16x8*)&Qb[kk * 32 + lg * 8];

    f32x4 oacc[8] = {};
    float mrow[4], lsum[4];
#pragma unroll
    for (int r = 0; r < 4; ++r) { mrow[r] = -1e30f; lsum[r] = 0.f; }

    for (int kt = 0; kt <= qt; ++kt) {
      const size_t kv0 = (size_t)kt * 64;
#pragma unroll
      for (int i = 0; i < 4; ++i)
        gld_lds16(kp + (kv0 + i * 16) * QKVN, &Ks[i * 2048 + wbase]);
#pragma unroll
      for (int i = 0; i < 4; ++i)
        gld_lds16(vp + (size_t)i * 32 * SEQ + kv0, &Vs[i * 2048 + wbase]);
      __syncthreads();

      // S = Q K^T
      f32x4 sc[4] = {};
      __builtin_amdgcn_s_setprio(1);
#pragma unroll
      for (int kk = 0; kk < 4; ++kk)
#pragma unroll
        for (int n = 0; n < 4; ++n) {
          bf16x8 kf = *(const bf16x8*)&Ks[(n * 16 + lr) * 128 + ((kk * 4 + lg) ^ sw) * 8];
          sc[n] = __builtin_amdgcn_mfma_f32_16x16x32_bf16(qf[kk], kf, sc[n], 0, 0, 0);
        }
      __builtin_amdgcn_s_setprio(0);

      if (kt == qt) {  // diagonal tile: causal mask
#pragma unroll
        for (int n = 0; n < 4; ++n)
#pragma unroll
          for (int r = 0; r < 4; ++r)
            if (n * 16 + lr > w * 16 + lg * 4 + r) sc[n][r] = -1e30f;
      }

      // online softmax with defer-max (T13, THR=8)
      float pml[4];
      float need = -1e30f;
#pragma unroll
      for (int r = 0; r < 4; ++r) {
        pml[r] = fmaxf(fmaxf(sc[0][r], sc[1][r]), fmaxf(sc[2][r], sc[3][r]));
        need = fmaxf(need, pml[r] - mrow[r]);
      }
      if (__all(need <= 8.0f)) {
#pragma unroll
        for (int r = 0; r < 4; ++r) {
          float ps = 0.f;
#pragma unroll
          for (int n = 0; n < 4; ++n) { sc[n][r] = __expf(sc[n][r] - mrow[r]); ps += sc[n][r]; }
#pragma unroll
          for (int off = 8; off > 0; off >>= 1) ps += __shfl_xor(ps, off);
          lsum[r] += ps;
        }
      } else {
#pragma unroll
        for (int r = 0; r < 4; ++r) {
          float pm = pml[r];
#pragma unroll
          for (int off = 8; off > 0; off >>= 1) pm = fmaxf(pm, __shfl_xor(pm, off));
          float mn = fmaxf(mrow[r], pm);
          float corr = __expf(mrow[r] - mn);
          mrow[r] = mn;
          float ps = 0.f;
#pragma unroll
          for (int n = 0; n < 4; ++n) { sc[n][r] = __expf(sc[n][r] - mn); ps += sc[n][r]; }
#pragma unroll
          for (int off = 8; off > 0; off >>= 1) ps += __shfl_xor(ps, off);
          lsum[r] = lsum[r] * corr + ps;
#pragma unroll
          for (int dn = 0; dn < 8; ++dn) oacc[dn][r] *= corr;
        }
      }

      // P -> LDS (swizzled)
#pragma unroll
      for (int n = 0; n < 4; ++n)
#pragma unroll
        for (int r = 0; r < 4; ++r) {
          int row = lg * 4 + r;
          Ps[w][row * 64 + (((n * 2 + (lr >> 3)) ^ (row & 7)) * 8) + (lr & 7)] = (__bf16)sc[n][r];
        }

      // O += P V
      __builtin_amdgcn_s_setprio(1);
#pragma unroll
      for (int ks = 0; ks < 2; ++ks) {
        bf16x8 pf = *(const bf16x8*)&Ps[w][lr * 64 + ((ks * 4 + lg) ^ sw) * 8];
#pragma unroll
        for (int dn = 0; dn < 8; ++dn) {
          bf16x8 vf = *(const bf16x8*)&Vs[(dn * 16 + lr) * 64 + ((ks * 4 + lg) ^ sw) * 8];
          oacc[dn] = __builtin_amdgcn_mfma_f32_16x16x32_bf16(pf, vf, oacc[dn], 0, 0, 0);
        }
      }
      __builtin_amdgcn_s_setprio(0);
      __syncthreads();
    }

    float inv[4];
#pragma unroll
    for (int r = 0; r < 4; ++r) inv[r] = __builtin_amdgcn_rcpf(lsum[r]);
    __bf16* Ob = attno + (size_t)(b * SEQ + qt * 64 + w * 16) * DIMSZ + h * 128;
#pragma unroll
    for (int dn = 0; dn < 8; ++dn)
#pragma unroll
      for (int r = 0; r < 4; ++r)
        Ob[(size_t)(lg * 4 + r) * DIMSZ + dn * 16 + lr] = (__bf16)(oacc[dn][r] * inv[r]);
  }
}

// ---------------- host launcher --------------------------------------------
extern "C" void kernel_launch(void* const* d_in, const int* in_sizes, int n_in,
                              void* d_out, int out_size, void* d_ws, size_t ws_size,
                              hipStream_t stream) {
  const float* x    = (const float*)d_in[0];
  const float* wq   = (const float*)d_in[1];
  const float* wk   = (const float*)d_in[2];
  const float* wv   = (const float*)d_in[3];
  const float* wo   = (const float*)d_in[4];
  const float* cosT = (const float*)d_in[5];
  const float* sinT = (const float*)d_in[6];
  // d_in[7] (mask) implemented as causal; d_in[8] (start_pos) == 0.

  char* ws = (char*)d_ws;
  __bf16* xb    = (__bf16*)(ws);                    // 4096x4096        (32 MiB)
  __bf16* wqkvb = (__bf16*)(ws + 33554432);         // 6144x4096        (48 MiB)
  __bf16* qkvb  = (__bf16*)(ws + 83886080);         // 4096x6144        (48 MiB)
  __bf16* wob   = (__bf16*)(ws + 134217728);        // 4096x4096        (32 MiB)
  __bf16* vt    = (__bf16*)(ws + 167772160);        // 16x128x2048      ( 8 MiB)
  __bf16* attno = (__bf16*)(ws + 176160768);        // 4096x4096        (32 MiB)
  float* out = (float*)d_out;

  // fp32 -> bf16 conversions, single merged launch
  k_cvt5<<<4096, 256, 0, stream>>>(x, wq, wk, wv, wo, xb, wqkvb, wob);

  // QKV projection: M=4096, N=6144 -> grid (24, 16), bn fastest
  k_gemm8p<__bf16><<<dim3(24, 16), 512, 0, stream>>>(xb, wqkvb, qkvb, 4096, QKVN, 4096);
  // RoPE + RMSNorm on Q,K (in place), attention scale folded into Q
  k_rope_norm<<<40960, 256, 0, stream>>>(qkvb, cosT, sinT);
  // V -> V^T for contiguous PV operand reads
  k_transpose_v<<<dim3(32, 16), 256, 0, stream>>>(qkvb, vt);
  // causal GQA flash attention (paired q-tiles for balance)
  k_flash<<<dim3(16, 64), 256, 0, stream>>>(qkvb, vt, attno);
  // output projection: M=4096, N=4096 -> grid (16, 16)
  k_gemm8p<float><<<dim3(16, 16), 512, 0, stream>>>(attno, wob, out, 4096, DIMSZ, 4096);
}